// Round 1
// baseline (2034.050 us; speedup 1.0000x reference)
//
#include <hip/hip_runtime.h>

#define NN 8
#define TT 8
#define LL 257
#define HH 16
#define CC 64
#define DD 1024
#define QQ 256
#define NQ (NN*QQ)   // 2048

static __device__ __forceinline__ float4 ld4(const float* p) { return *(const float4*)p; }

// ---------------------------------------------------------------- LN ----
__global__ __launch_bounds__(256) void ln_kernel(const float* __restrict__ in,
    const float* __restrict__ w, const float* __restrict__ b, float* __restrict__ out) {
  __shared__ float red[16];
  const int tid = threadIdx.x;
  const size_t row = blockIdx.x;
  const float4 v = ((const float4*)(in + row * DD))[tid];
  float s  = v.x + v.y + v.z + v.w;
  float ss = v.x*v.x + v.y*v.y + v.z*v.z + v.w*v.w;
  #pragma unroll
  for (int off = 32; off; off >>= 1) { s += __shfl_xor(s, off); ss += __shfl_xor(ss, off); }
  if ((tid & 63) == 0) { red[tid >> 6] = s; red[8 + (tid >> 6)] = ss; }
  __syncthreads();
  s  = red[0] + red[1] + red[2] + red[3];
  ss = red[8] + red[9] + red[10] + red[11];
  const float mean = s * (1.f / DD);
  const float var  = ss * (1.f / DD) - mean * mean;
  const float inv  = rsqrtf(var + 1e-5f);
  const float4 wv = ((const float4*)w)[tid];
  const float4 bv = ((const float4*)b)[tid];
  float4 ov;
  ov.x = (v.x - mean) * inv * wv.x + bv.x;
  ov.y = (v.y - mean) * inv * wv.y + bv.y;
  ov.z = (v.z - mean) * inv * wv.z + bv.z;
  ov.w = (v.w - mean) * inv * wv.w + bv.w;
  ((float4*)(out + row * DD))[tid] = ov;
}

// ------------------------------------------------------- te adaptor ----
// one block per t row: _te = te + LN(te)@l1.T@l2.T
__global__ __launch_bounds__(256) void adaptor_te_kernel(
    const float* __restrict__ te, const float* __restrict__ lnw, const float* __restrict__ lnb,
    const float* __restrict__ l1, const float* __restrict__ l2, float* __restrict__ out) {
  __shared__ float hsh[1024];
  __shared__ float midsh[128];
  __shared__ float red[16];
  const int t = blockIdx.x, tid = threadIdx.x;
  const float4 v = ((const float4*)(te + (size_t)t * DD))[tid];
  float s  = v.x + v.y + v.z + v.w;
  float ss = v.x*v.x + v.y*v.y + v.z*v.z + v.w*v.w;
  #pragma unroll
  for (int off = 32; off; off >>= 1) { s += __shfl_xor(s, off); ss += __shfl_xor(ss, off); }
  if ((tid & 63) == 0) { red[tid >> 6] = s; red[8 + (tid >> 6)] = ss; }
  __syncthreads();
  s  = red[0] + red[1] + red[2] + red[3];
  ss = red[8] + red[9] + red[10] + red[11];
  const float mean = s * (1.f / DD), var = ss * (1.f / DD) - mean * mean;
  const float inv = rsqrtf(var + 1e-5f);
  const float4 w4 = ((const float4*)lnw)[tid], b4 = ((const float4*)lnb)[tid];
  float4 hv;
  hv.x = (v.x - mean) * inv * w4.x + b4.x;
  hv.y = (v.y - mean) * inv * w4.y + b4.y;
  hv.z = (v.z - mean) * inv * w4.z + b4.z;
  hv.w = (v.w - mean) * inv * w4.w + b4.w;
  ((float4*)hsh)[tid] = hv;
  __syncthreads();
  // mid[j] = h . l1[j], two threads per j
  const int j = tid >> 1, p = tid & 1;
  const float* l1r = l1 + (size_t)j * DD + p * 512;
  const float* hp  = hsh + p * 512;
  float acc = 0.f;
  for (int i = 0; i < 512; i += 4) {
    const float4 a  = ld4(l1r + i);
    const float4 hh = ld4(hp + i);
    acc += a.x*hh.x + a.y*hh.y + a.z*hh.z + a.w*hh.w;
  }
  acc += __shfl_xor(acc, 1);
  if (p == 0) midsh[j] = acc;
  __syncthreads();
  float o4[4];
  #pragma unroll
  for (int c = 0; c < 4; ++c) {
    const int dd = tid * 4 + c;
    const float* l2r = l2 + (size_t)dd * 128;
    float a = 0.f;
    for (int jj = 0; jj < 128; jj += 4) {
      const float4 mm = ld4(midsh + jj);
      const float4 ww = ld4(l2r + jj);
      a += mm.x*ww.x + mm.y*ww.y + mm.z*ww.z + mm.w*ww.w;
    }
    o4[c] = a;
  }
  *(float4*)(out + (size_t)t * DD + tid * 4) =
      make_float4(o4[0] + v.x, o4[1] + v.y, o4[2] + v.z, o4[3] + v.w);
}

// ----------------------------------------------------------- te k/v ----
// te_k[t][d] = _te[t] . W[1024+d] + b[1024+d];  te_v uses rows 2048..3071
__global__ __launch_bounds__(256) void te_kv_kernel(
    const float* __restrict__ _te, const float* __restrict__ W, const float* __restrict__ bias,
    float* __restrict__ tek, float* __restrict__ tev) {
  __shared__ float tes[8 * 1024];
  const int tid = threadIdx.x;
  for (int i = tid; i < 2048; i += 256) ((float4*)tes)[i] = ((const float4*)_te)[i];
  __syncthreads();
  const int idx = blockIdx.x * 256 + tid;   // 0..2047
  const float* wr = W + (size_t)(1024 + idx) * DD;
  float acc[8] = {0.f,0.f,0.f,0.f,0.f,0.f,0.f,0.f};
  for (int kk = 0; kk < DD; kk += 4) {
    const float4 w4 = ld4(wr + kk);
    #pragma unroll
    for (int t = 0; t < 8; ++t) {
      const float4 h4 = ld4(tes + t * 1024 + kk);
      acc[t] += w4.x*h4.x + w4.y*h4.y + w4.z*h4.z + w4.w*h4.w;
    }
  }
  const float bv = bias[1024 + idx];
  #pragma unroll
  for (int t = 0; t < 8; ++t) {
    if (idx < 1024) tek[(size_t)t * DD + idx] = acc[t] + bv;
    else            tev[(size_t)t * DD + (idx - 1024)] = acc[t] + bv;
  }
}

// ------------------------------------------------------------- GEMM ----
// C[M,N] = epi(A[M,K] @ W[N,K]^T)
// EPI: 0 plain | 1 (x+bias)*0.125 | 2 quickgelu(x+bias) | 3 x+bias+res | 4 x+res
template<int EPI>
__global__ __launch_bounds__(256) void gemm_f32(
    const float* __restrict__ A, const float* __restrict__ W,
    const float* __restrict__ bias, const float* __restrict__ res,
    float* __restrict__ C, int M, int N, int K) {
  constexpr int BM = 128, BN = 128, BK = 16;
  __shared__ float As[BK][BM + 4];
  __shared__ float Bs[BK][BN + 4];
  const int tid = threadIdx.x;
  const int tx = tid & 15, ty = tid >> 4;
  const int m0 = blockIdx.y * BM, n0 = blockIdx.x * BN;
  const int lrow = tid >> 1;
  const int lseg = (tid & 1) * 8;
  const float* Ap = A + (size_t)(m0 + lrow) * K + lseg;
  const float* Wp = W + (size_t)(n0 + lrow) * K + lseg;
  float acc[8][8] = {};
  for (int k0 = 0; k0 < K; k0 += BK) {
    const float4 a0 = ld4(Ap + k0), a1 = ld4(Ap + k0 + 4);
    const float4 b0 = ld4(Wp + k0), b1 = ld4(Wp + k0 + 4);
    __syncthreads();
    As[lseg+0][lrow]=a0.x; As[lseg+1][lrow]=a0.y; As[lseg+2][lrow]=a0.z; As[lseg+3][lrow]=a0.w;
    As[lseg+4][lrow]=a1.x; As[lseg+5][lrow]=a1.y; As[lseg+6][lrow]=a1.z; As[lseg+7][lrow]=a1.w;
    Bs[lseg+0][lrow]=b0.x; Bs[lseg+1][lrow]=b0.y; Bs[lseg+2][lrow]=b0.z; Bs[lseg+3][lrow]=b0.w;
    Bs[lseg+4][lrow]=b1.x; Bs[lseg+5][lrow]=b1.y; Bs[lseg+6][lrow]=b1.z; Bs[lseg+7][lrow]=b1.w;
    __syncthreads();
    #pragma unroll
    for (int kk = 0; kk < BK; ++kk) {
      const float4 av0 = *(const float4*)&As[kk][ty*8];
      const float4 av1 = *(const float4*)&As[kk][ty*8+4];
      const float4 bv0 = *(const float4*)&Bs[kk][tx*8];
      const float4 bv1 = *(const float4*)&Bs[kk][tx*8+4];
      const float a[8]  = {av0.x,av0.y,av0.z,av0.w,av1.x,av1.y,av1.z,av1.w};
      const float bb[8] = {bv0.x,bv0.y,bv0.z,bv0.w,bv1.x,bv1.y,bv1.z,bv1.w};
      #pragma unroll
      for (int i = 0; i < 8; ++i)
        #pragma unroll
        for (int jj = 0; jj < 8; ++jj)
          acc[i][jj] += a[i] * bb[jj];
    }
  }
  const int nb = n0 + tx * 8;
  float bias8[8] = {};
  if (EPI == 1 || EPI == 2 || EPI == 3) {
    #pragma unroll
    for (int jj = 0; jj < 8; ++jj) bias8[jj] = bias[nb + jj];
  }
  #pragma unroll
  for (int i = 0; i < 8; ++i) {
    const size_t off = (size_t)(m0 + ty * 8 + i) * N + nb;
    float v[8];
    #pragma unroll
    for (int jj = 0; jj < 8; ++jj) {
      float x = acc[i][jj];
      if (EPI == 1) x = (x + bias8[jj]) * 0.125f;
      else if (EPI == 2) { x += bias8[jj]; x = x / (1.f + __expf(-1.702f * x)); }
      else if (EPI == 3) x += bias8[jj] + res[off + jj];
      else if (EPI == 4) x += res[off + jj];
      v[jj] = x;
    }
    *(float4*)(C + off)     = make_float4(v[0], v[1], v[2], v[3]);
    *(float4*)(C + off + 4) = make_float4(v[4], v[5], v[6], v[7]);
  }
}

// -------------------------------------------------------- attention ----
// grid (h, t, n); 256 threads, thread = q row. K/V staged in 64 KiB LDS in
// two 128-row chunks, float4 columns XOR-swizzled by row for conflict-free
// staging writes; compute reads are wave-uniform (broadcast).
__global__ __launch_bounds__(256) void attn_kernel(
    const float* __restrict__ ak, const float* __restrict__ av,
    const float* __restrict__ sq, const float* __restrict__ tek,
    const float* __restrict__ tev, const float* __restrict__ mask,
    float* __restrict__ smix) {
  const int h = blockIdx.x, t = blockIdx.y, n = blockIdx.z;
  const int tid = threadIdx.x;
  __shared__ float Ks[128][64];
  __shared__ float Vs[128][64];
  float4 q4[16], acc4[16];
  {
    const float4* qp = (const float4*)(sq + ((size_t)(n * QQ + tid)) * DD + h * CC);
    #pragma unroll
    for (int i = 0; i < 16; ++i) q4[i] = qp[i];
  }
  #pragma unroll
  for (int i = 0; i < 16; ++i) acc4[i] = make_float4(0.f, 0.f, 0.f, 0.f);
  float m = -1e30f, l = 0.f;
  const float* mrow = mask + (size_t)tid * QQ;
  const int r  = tid >> 1;
  const int ch = (tid & 1) * 32;
  const size_t kbase0 = ((((size_t)n * TT + t) * LL + 1) * HH + h) * CC;
  for (int c0 = 0; c0 < 256; c0 += 128) {
    __syncthreads();
    {
      const float4* kp  = (const float4*)(ak + kbase0 + (size_t)(c0 + r) * HH * CC + ch);
      const float4* vp  = (const float4*)(av + kbase0 + (size_t)(c0 + r) * HH * CC + ch);
      const float4* tkp = (const float4*)(tek + (size_t)t * DD + h * CC + ch);
      const float4* tvp = (const float4*)(tev + (size_t)t * DD + h * CC + ch);
      #pragma unroll
      for (int i = 0; i < 8; ++i) {
        const int c4 = (ch >> 2) + i;
        const int sw = c4 ^ (r & 15);
        float4 kv = kp[i]; const float4 tk = tkp[i];
        kv.x += tk.x; kv.y += tk.y; kv.z += tk.z; kv.w += tk.w;
        ((float4*)Ks[r])[sw] = kv;
        float4 vv = vp[i]; const float4 tv = tvp[i];
        vv.x += tv.x; vv.y += tv.y; vv.z += tv.z; vv.w += tv.w;
        ((float4*)Vs[r])[sw] = vv;
      }
    }
    __syncthreads();
    for (int kb = 0; kb < 128; kb += 8) {
      float sv[8];
      #pragma unroll
      for (int jj = 0; jj < 8; ++jj) {
        const int k = kb + jj;
        const float4* krow = (const float4*)Ks[k];
        const int sx = k & 15;
        float p0 = 0.f, p1 = 0.f, p2 = 0.f, p3 = 0.f;
        #pragma unroll
        for (int i = 0; i < 16; ++i) {
          const float4 kv = krow[i ^ sx];
          p0 += q4[i].x * kv.x; p1 += q4[i].y * kv.y;
          p2 += q4[i].z * kv.z; p3 += q4[i].w * kv.w;
        }
        sv[jj] = (p0 + p1) + (p2 + p3) + mrow[c0 + k];
      }
      float mx = sv[0];
      #pragma unroll
      for (int jj = 1; jj < 8; ++jj) mx = fmaxf(mx, sv[jj]);
      if (mx > m) {
        const float sc = __expf(m - mx);
        l *= sc;
        #pragma unroll
        for (int i = 0; i < 16; ++i) {
          acc4[i].x *= sc; acc4[i].y *= sc; acc4[i].z *= sc; acc4[i].w *= sc;
        }
        m = mx;
      }
      #pragma unroll
      for (int jj = 0; jj < 8; ++jj) {
        const float p = __expf(sv[jj] - m);
        l += p;
        const float4* vrow = (const float4*)Vs[kb + jj];
        const int sx = (kb + jj) & 15;
        #pragma unroll
        for (int i = 0; i < 16; ++i) {
          const float4 vv = vrow[i ^ sx];
          acc4[i].x += p * vv.x; acc4[i].y += p * vv.y;
          acc4[i].z += p * vv.z; acc4[i].w += p * vv.w;
        }
      }
    }
  }
  const float inv = 1.f / l;
  float* op = smix + (((size_t)(n * TT + t) * QQ + tid) * HH + h) * CC;
  #pragma unroll
  for (int i = 0; i < 16; ++i) {
    float4 o = acc4[i];
    o.x *= inv; o.y *= inv; o.z *= inv; o.w *= inv;
    ((float4*)op)[i] = o;
  }
}

// -------------------------------------------- conv3+mean_t combine ----
// mean_t(conv(xm)+b+xm) = ((1+w0+w1+w2)*S - w0*xm[t=7] - w2*xm[t=0])/8 + b
__global__ __launch_bounds__(256) void combine_kernel(
    const float* __restrict__ smix, const float* __restrict__ cw,
    const float* __restrict__ cb, float* __restrict__ smm) {
  const int nq = blockIdx.x;
  const int d = threadIdx.x * 4;
  const int n = nq >> 8, q = nq & 255;
  const float* base = smix + ((size_t)n * TT * QQ + q) * DD + d;
  float4 S = make_float4(0.f, 0.f, 0.f, 0.f);
  float4 x0 = make_float4(0.f, 0.f, 0.f, 0.f), x7 = x0;
  #pragma unroll
  for (int t = 0; t < TT; ++t) {
    const float4 v = *(const float4*)(base + (size_t)t * QQ * DD);
    if (t == 0) x0 = v;
    if (t == 7) x7 = v;
    S.x += v.x; S.y += v.y; S.z += v.z; S.w += v.w;
  }
  const float Sa[4] = {S.x, S.y, S.z, S.w};
  const float X0[4] = {x0.x, x0.y, x0.z, x0.w};
  const float X7[4] = {x7.x, x7.y, x7.z, x7.w};
  float o[4];
  #pragma unroll
  for (int i = 0; i < 4; ++i) {
    const int chn = d + i;
    const float w0 = cw[chn*3+0], w1 = cw[chn*3+1], w2 = cw[chn*3+2];
    o[i] = ((1.f + w0 + w1 + w2) * Sa[i] - w0 * X7[i] - w2 * X0[i]) * 0.125f + cb[chn];
  }
  *(float4*)(smm + (size_t)nq * DD + d) = make_float4(o[0], o[1], o[2], o[3]);
}

// ------------------------------------------------------------ launch ----
extern "C" void kernel_launch(void* const* d_in, const int* in_sizes, int n_in,
                              void* d_out, int out_size, void* d_ws, size_t ws_size,
                              hipStream_t stream) {
  const float* attrs_k = (const float*)d_in[0];
  const float* attrs_v = (const float*)d_in[1];
  const float* s       = (const float*)d_in[2];
  const float* te      = (const float*)d_in[3];
  const float* pmask   = (const float*)d_in[4];
  const float* ln1_w   = (const float*)d_in[5];
  const float* ln1_b   = (const float*)d_in[6];
  const float* inW     = (const float*)d_in[7];
  const float* inB     = (const float*)d_in[8];
  const float* outW    = (const float*)d_in[9];
  const float* outB    = (const float*)d_in[10];
  const float* ln2_w   = (const float*)d_in[11];
  const float* ln2_b   = (const float*)d_in[12];
  const float* fcW     = (const float*)d_in[13];
  const float* fcB     = (const float*)d_in[14];
  const float* pjW     = (const float*)d_in[15];
  const float* pjB     = (const float*)d_in[16];
  const float* sylnW   = (const float*)d_in[17];
  const float* sylnB   = (const float*)d_in[18];
  const float* syl1    = (const float*)d_in[19];
  const float* syl2    = (const float*)d_in[20];
  const float* telnW   = (const float*)d_in[21];
  const float* telnB   = (const float*)d_in[22];
  const float* tel1    = (const float*)d_in[23];
  const float* tel2    = (const float*)d_in[24];
  const float* tconvW  = (const float*)d_in[25];
  const float* tconvB  = (const float*)d_in[26];

  float* ws    = (float*)d_ws;
  float* f_te  = ws;                  //   8192
  float* f_tek = ws + 8192;           //   8192
  float* f_tev = ws + 16384;          //   8192
  float* f_mid = ws + 24576;          // 262144
  float* bufA  = ws + 524288;         // 2097152: LN outputs (h, x, x2)
  float* bufB  = bufA + 2097152;      // 2097152: _s, later smm
  float* bufC  = bufB + 2097152;      // 2097152: s_q (pre-scaled)
  float* smix  = bufC + 2097152;      // 16777216
  float* hmid  = smix;                // 8388608  (smix dead by then)
  float* s1    = smix + 8388608;      // 2097152  (smix dead by then)
  float* outp  = (float*)d_out;

  // 1. te adaptor
  adaptor_te_kernel<<<TT, 256, 0, stream>>>(te, telnW, telnB, tel1, tel2, f_te);
  // 2. te_k / te_v projection
  te_kv_kernel<<<8, 256, 0, stream>>>(f_te, inW, inB, f_tek, f_tev);
  // 3. syno adaptor: h = LN(s)
  ln_kernel<<<NQ, 256, 0, stream>>>(s, sylnW, sylnB, bufA);
  // 4. mid = h @ l1^T
  gemm_f32<0><<<dim3(1, 16), 256, 0, stream>>>(bufA, syl1, nullptr, nullptr, f_mid, NQ, 128, DD);
  // 5. _s = s + mid @ l2^T
  gemm_f32<4><<<dim3(8, 16), 256, 0, stream>>>(f_mid, syl2, nullptr, s, bufB, NQ, DD, 128);
  // 6. x = LN1(_s)
  ln_kernel<<<NQ, 256, 0, stream>>>(bufB, ln1_w, ln1_b, bufA);
  // 7. s_q = (x @ Wq^T + bq) * 0.125
  gemm_f32<1><<<dim3(8, 16), 256, 0, stream>>>(bufA, inW, inB, nullptr, bufC, NQ, DD, DD);
  // 8. attention -> smix [n][t][q][h][c]
  attn_kernel<<<dim3(HH, TT, NN), 256, 0, stream>>>(attrs_k, attrs_v, bufC, f_tek, f_tev, pmask, smix);
  // 9. conv+mean combine -> smm
  combine_kernel<<<NQ, 256, 0, stream>>>(smix, tconvW, tconvB, bufB);
  // 10. s1 = s + smm @ outW^T + outB
  gemm_f32<3><<<dim3(8, 16), 256, 0, stream>>>(bufB, outW, outB, s, s1, NQ, DD, DD);
  // 11. x2 = LN2(s1)
  ln_kernel<<<NQ, 256, 0, stream>>>(s1, ln2_w, ln2_b, bufA);
  // 12. hmid = qgelu(x2 @ fcW^T + fcB)
  gemm_f32<2><<<dim3(32, 16), 256, 0, stream>>>(bufA, fcW, fcB, nullptr, hmid, NQ, 4 * DD, DD);
  // 13. out = s1 + hmid @ pjW^T + pjB
  gemm_f32<3><<<dim3(8, 16), 256, 0, stream>>>(hmid, pjW, pjB, s1, outp, NQ, DD, 4 * DD);
}

// Round 2
// 718.113 us; speedup vs baseline: 2.8325x; 2.8325x over previous
//
#include <hip/hip_runtime.h>

#define NN 8
#define TT 8
#define LL 257
#define HH 16
#define CC 64
#define DD 1024
#define QQ 256
#define NQ (NN*QQ)   // 2048

typedef __attribute__((ext_vector_type(4))) float f32x4;
typedef __attribute__((ext_vector_type(4))) unsigned int u32x4;
typedef __attribute__((ext_vector_type(2))) unsigned int u32x2;

static __device__ __forceinline__ float4 ld4(const float* p) { return *(const float4*)p; }

static __device__ __forceinline__ void mfma16(f32x4& d, u32x4 a, u32x4 b) {
  // D = A(16x32) * B(32x16) + D, bf16 inputs
  asm("v_mfma_f32_16x16x32_bf16 %0, %1, %2, %0" : "+v"(d) : "v"(a), "v"(b));
}

static __device__ __forceinline__ unsigned int f2bf(float x) {
  unsigned int u = __float_as_uint(x);
  return (u + 0x7fffu + ((u >> 16) & 1u)) >> 16;
}
static __device__ __forceinline__ unsigned int pk2(float lo, float hi) {
  return f2bf(lo) | (f2bf(hi) << 16);
}

// ---------------------------------------------------------------- LN ----
__global__ __launch_bounds__(256) void ln_kernel(const float* __restrict__ in,
    const float* __restrict__ w, const float* __restrict__ b, float* __restrict__ out) {
  __shared__ float red[16];
  const int tid = threadIdx.x;
  const size_t row = blockIdx.x;
  const float4 v = ((const float4*)(in + row * DD))[tid];
  float s  = v.x + v.y + v.z + v.w;
  float ss = v.x*v.x + v.y*v.y + v.z*v.z + v.w*v.w;
  #pragma unroll
  for (int off = 32; off; off >>= 1) { s += __shfl_xor(s, off); ss += __shfl_xor(ss, off); }
  if ((tid & 63) == 0) { red[tid >> 6] = s; red[8 + (tid >> 6)] = ss; }
  __syncthreads();
  s  = red[0] + red[1] + red[2] + red[3];
  ss = red[8] + red[9] + red[10] + red[11];
  const float mean = s * (1.f / DD);
  const float var  = ss * (1.f / DD) - mean * mean;
  const float inv  = rsqrtf(var + 1e-5f);
  const float4 wv = ((const float4*)w)[tid];
  const float4 bv = ((const float4*)b)[tid];
  float4 ov;
  ov.x = (v.x - mean) * inv * wv.x + bv.x;
  ov.y = (v.y - mean) * inv * wv.y + bv.y;
  ov.z = (v.z - mean) * inv * wv.z + bv.z;
  ov.w = (v.w - mean) * inv * wv.w + bv.w;
  ((float4*)(out + row * DD))[tid] = ov;
}

// ------------------------------------------------------- te adaptor ----
__global__ __launch_bounds__(256) void adaptor_te_kernel(
    const float* __restrict__ te, const float* __restrict__ lnw, const float* __restrict__ lnb,
    const float* __restrict__ l1, const float* __restrict__ l2, float* __restrict__ out) {
  __shared__ float hsh[1024];
  __shared__ float midsh[128];
  __shared__ float red[16];
  const int t = blockIdx.x, tid = threadIdx.x;
  const float4 v = ((const float4*)(te + (size_t)t * DD))[tid];
  float s  = v.x + v.y + v.z + v.w;
  float ss = v.x*v.x + v.y*v.y + v.z*v.z + v.w*v.w;
  #pragma unroll
  for (int off = 32; off; off >>= 1) { s += __shfl_xor(s, off); ss += __shfl_xor(ss, off); }
  if ((tid & 63) == 0) { red[tid >> 6] = s; red[8 + (tid >> 6)] = ss; }
  __syncthreads();
  s  = red[0] + red[1] + red[2] + red[3];
  ss = red[8] + red[9] + red[10] + red[11];
  const float mean = s * (1.f / DD), var = ss * (1.f / DD) - mean * mean;
  const float inv = rsqrtf(var + 1e-5f);
  const float4 w4 = ((const float4*)lnw)[tid], b4 = ((const float4*)lnb)[tid];
  float4 hv;
  hv.x = (v.x - mean) * inv * w4.x + b4.x;
  hv.y = (v.y - mean) * inv * w4.y + b4.y;
  hv.z = (v.z - mean) * inv * w4.z + b4.z;
  hv.w = (v.w - mean) * inv * w4.w + b4.w;
  ((float4*)hsh)[tid] = hv;
  __syncthreads();
  const int j = tid >> 1, p = tid & 1;
  const float* l1r = l1 + (size_t)j * DD + p * 512;
  const float* hp  = hsh + p * 512;
  float acc = 0.f;
  for (int i = 0; i < 512; i += 4) {
    const float4 a  = ld4(l1r + i);
    const float4 hh = ld4(hp + i);
    acc += a.x*hh.x + a.y*hh.y + a.z*hh.z + a.w*hh.w;
  }
  acc += __shfl_xor(acc, 1);
  if (p == 0) midsh[j] = acc;
  __syncthreads();
  float o4[4];
  #pragma unroll
  for (int c = 0; c < 4; ++c) {
    const int dd = tid * 4 + c;
    const float* l2r = l2 + (size_t)dd * 128;
    float a = 0.f;
    for (int jj = 0; jj < 128; jj += 4) {
      const float4 mm = ld4(midsh + jj);
      const float4 ww = ld4(l2r + jj);
      a += mm.x*ww.x + mm.y*ww.y + mm.z*ww.z + mm.w*ww.w;
    }
    o4[c] = a;
  }
  *(float4*)(out + (size_t)t * DD + tid * 4) =
      make_float4(o4[0] + v.x, o4[1] + v.y, o4[2] + v.z, o4[3] + v.w);
}

// ----------------------------------------------------------- te k/v ----
__global__ __launch_bounds__(256) void te_kv_kernel(
    const float* __restrict__ _te, const float* __restrict__ W, const float* __restrict__ bias,
    float* __restrict__ tek, float* __restrict__ tev) {
  __shared__ float tes[8 * 1024];
  const int tid = threadIdx.x;
  for (int i = tid; i < 2048; i += 256) ((float4*)tes)[i] = ((const float4*)_te)[i];
  __syncthreads();
  const int idx = blockIdx.x * 256 + tid;   // 0..2047
  const float* wr = W + (size_t)(1024 + idx) * DD;
  float acc[8] = {0.f,0.f,0.f,0.f,0.f,0.f,0.f,0.f};
  for (int kk = 0; kk < DD; kk += 4) {
    const float4 w4 = ld4(wr + kk);
    #pragma unroll
    for (int t = 0; t < 8; ++t) {
      const float4 h4 = ld4(tes + t * 1024 + kk);
      acc[t] += w4.x*h4.x + w4.y*h4.y + w4.z*h4.z + w4.w*h4.w;
    }
  }
  const float bv = bias[1024 + idx];
  #pragma unroll
  for (int t = 0; t < 8; ++t) {
    if (idx < 1024) tek[(size_t)t * DD + idx] = acc[t] + bv;
    else            tev[(size_t)t * DD + (idx - 1024)] = acc[t] + bv;
  }
}

// --------------------------------------------------- f32 GEMM (small) ----
// EPI: 0 plain | 4 x+res
template<int EPI>
__global__ __launch_bounds__(256) void gemm_f32(
    const float* __restrict__ A, const float* __restrict__ W,
    const float* __restrict__ bias, const float* __restrict__ res,
    float* __restrict__ C, int M, int N, int K) {
  constexpr int BM = 128, BN = 128, BK = 16;
  __shared__ float As[BK][BM + 4];
  __shared__ float Bs[BK][BN + 4];
  const int tid = threadIdx.x;
  const int tx = tid & 15, ty = tid >> 4;
  const int m0 = blockIdx.y * BM, n0 = blockIdx.x * BN;
  const int lrow = tid >> 1;
  const int lseg = (tid & 1) * 8;
  const float* Ap = A + (size_t)(m0 + lrow) * K + lseg;
  const float* Wp = W + (size_t)(n0 + lrow) * K + lseg;
  float acc[8][8] = {};
  for (int k0 = 0; k0 < K; k0 += BK) {
    const float4 a0 = ld4(Ap + k0), a1 = ld4(Ap + k0 + 4);
    const float4 b0 = ld4(Wp + k0), b1 = ld4(Wp + k0 + 4);
    __syncthreads();
    As[lseg+0][lrow]=a0.x; As[lseg+1][lrow]=a0.y; As[lseg+2][lrow]=a0.z; As[lseg+3][lrow]=a0.w;
    As[lseg+4][lrow]=a1.x; As[lseg+5][lrow]=a1.y; As[lseg+6][lrow]=a1.z; As[lseg+7][lrow]=a1.w;
    Bs[lseg+0][lrow]=b0.x; Bs[lseg+1][lrow]=b0.y; Bs[lseg+2][lrow]=b0.z; Bs[lseg+3][lrow]=b0.w;
    Bs[lseg+4][lrow]=b1.x; Bs[lseg+5][lrow]=b1.y; Bs[lseg+6][lrow]=b1.z; Bs[lseg+7][lrow]=b1.w;
    __syncthreads();
    #pragma unroll
    for (int kk = 0; kk < BK; ++kk) {
      const float4 av0 = *(const float4*)&As[kk][ty*8];
      const float4 av1 = *(const float4*)&As[kk][ty*8+4];
      const float4 bv0 = *(const float4*)&Bs[kk][tx*8];
      const float4 bv1 = *(const float4*)&Bs[kk][tx*8+4];
      const float a[8]  = {av0.x,av0.y,av0.z,av0.w,av1.x,av1.y,av1.z,av1.w};
      const float bb[8] = {bv0.x,bv0.y,bv0.z,bv0.w,bv1.x,bv1.y,bv1.z,bv1.w};
      #pragma unroll
      for (int i = 0; i < 8; ++i)
        #pragma unroll
        for (int jj = 0; jj < 8; ++jj)
          acc[i][jj] += a[i] * bb[jj];
    }
  }
  const int nb = n0 + tx * 8;
  #pragma unroll
  for (int i = 0; i < 8; ++i) {
    const size_t off = (size_t)(m0 + ty * 8 + i) * N + nb;
    float v[8];
    #pragma unroll
    for (int jj = 0; jj < 8; ++jj) {
      float x = acc[i][jj];
      if (EPI == 4) x += res[off + jj];
      v[jj] = x;
    }
    *(float4*)(C + off)     = make_float4(v[0], v[1], v[2], v[3]);
    *(float4*)(C + off + 4) = make_float4(v[4], v[5], v[6], v[7]);
  }
}

// --------------------------------------------------- bf16 MFMA GEMM ----
// C[M,N] = epi(A[M,K] @ W[N,K]^T)
// EPI: 1 (x+b)*0.125 -> bf16 | 2 qgelu(x+b) -> bf16 | 3 x+b+res -> f32
// ABF: A operand is bf16 (else f32). W always f32.
template<int EPI, int ABF>
__global__ __launch_bounds__(256) void gemm_mfma(
    const void* __restrict__ Av, const float* __restrict__ Wv,
    const float* __restrict__ bias, const float* __restrict__ res,
    void* __restrict__ Cv, int M, int N, int K) {
  __shared__ unsigned short As[128][72];
  __shared__ unsigned short Bs[128][72];
  const int tid = threadIdx.x, w = tid >> 6, l = tid & 63;
  const int lc = l & 15, lg = l >> 4;
  const int m0 = blockIdx.y * 128, n0 = blockIdx.x * 128;
  const int wm = (w >> 1) * 64, wn = (w & 1) * 64;
  const int sr = tid >> 1, sseg = (tid & 1) * 32;
  f32x4 acc[4][4] = {};
  for (int k0 = 0; k0 < K; k0 += 64) {
    __syncthreads();
    if (ABF) {
      const unsigned short* Ap = (const unsigned short*)Av + (size_t)(m0 + sr) * K + k0 + sseg;
      u32x4 x0 = *(const u32x4*)Ap;        u32x4 x1 = *(const u32x4*)(Ap + 8);
      u32x4 x2 = *(const u32x4*)(Ap + 16); u32x4 x3 = *(const u32x4*)(Ap + 24);
      *(u32x4*)&As[sr][sseg]      = x0; *(u32x4*)&As[sr][sseg + 8]  = x1;
      *(u32x4*)&As[sr][sseg + 16] = x2; *(u32x4*)&As[sr][sseg + 24] = x3;
    } else {
      const float* Ap = (const float*)Av + (size_t)(m0 + sr) * K + k0 + sseg;
      #pragma unroll
      for (int q = 0; q < 4; ++q) {
        const float4 f0 = ld4(Ap + q * 8), f1 = ld4(Ap + q * 8 + 4);
        u32x4 pk; pk.x = pk2(f0.x, f0.y); pk.y = pk2(f0.z, f0.w);
        pk.z = pk2(f1.x, f1.y); pk.w = pk2(f1.z, f1.w);
        *(u32x4*)&As[sr][sseg + q * 8] = pk;
      }
    }
    {
      const float* Wp = Wv + (size_t)(n0 + sr) * K + k0 + sseg;
      #pragma unroll
      for (int q = 0; q < 4; ++q) {
        const float4 f0 = ld4(Wp + q * 8), f1 = ld4(Wp + q * 8 + 4);
        u32x4 pk; pk.x = pk2(f0.x, f0.y); pk.y = pk2(f0.z, f0.w);
        pk.z = pk2(f1.x, f1.y); pk.w = pk2(f1.z, f1.w);
        *(u32x4*)&Bs[sr][sseg + q * 8] = pk;
      }
    }
    __syncthreads();
    #pragma unroll
    for (int ks = 0; ks < 2; ++ks) {
      u32x4 af[4], bfr[4];
      #pragma unroll
      for (int i = 0; i < 4; ++i) af[i]  = *(const u32x4*)&As[wm + i*16 + lc][ks*32 + lg*8];
      #pragma unroll
      for (int j = 0; j < 4; ++j) bfr[j] = *(const u32x4*)&Bs[wn + j*16 + lc][ks*32 + lg*8];
      #pragma unroll
      for (int i = 0; i < 4; ++i)
        #pragma unroll
        for (int j = 0; j < 4; ++j)
          mfma16(acc[i][j], af[i], bfr[j]);
    }
  }
  float bias4[4];
  #pragma unroll
  for (int j = 0; j < 4; ++j) bias4[j] = bias ? bias[n0 + wn + j*16 + lc] : 0.f;
  #pragma unroll
  for (int i = 0; i < 4; ++i) {
    #pragma unroll
    for (int j = 0; j < 4; ++j) {
      const int col = n0 + wn + j*16 + lc;
      #pragma unroll
      for (int r = 0; r < 4; ++r) {
        const int row = m0 + wm + i*16 + lg*4 + r;
        float x = acc[i][j][r];
        if (EPI == 1) {
          x = (x + bias4[j]) * 0.125f;
          ((unsigned short*)Cv)[(size_t)row * N + col] = (unsigned short)f2bf(x);
        } else if (EPI == 2) {
          x += bias4[j];
          x = x / (1.f + __expf(-1.702f * x));
          ((unsigned short*)Cv)[(size_t)row * N + col] = (unsigned short)f2bf(x);
        } else {
          x += bias4[j] + res[(size_t)row * N + col];
          ((float*)Cv)[(size_t)row * N + col] = x;
        }
      }
    }
  }
}

// -------------------------------------------------- MFMA attention ----
// grid (h, t, n); 4 waves x 64 q-rows. Swapped QK^T (S^T = K@Q^T) so softmax
// rows are lane-local; P -> per-wave LDS bf16; PV as O^T = Vt @ P.
__global__ __launch_bounds__(256, 2) void attn_mfma(
    const float* __restrict__ ak, const float* __restrict__ av,
    const unsigned short* __restrict__ qbf,
    const float* __restrict__ tek, const float* __restrict__ tev,
    const float* __restrict__ mask, float* __restrict__ smix) {
  const int h = blockIdx.x, t = blockIdx.y, n = blockIdx.z;
  const int tid = threadIdx.x, w = tid >> 6, l = tid & 63;
  const int lc = l & 15, lg = l >> 4;
  __shared__ unsigned short Ks[64][72];
  __shared__ unsigned short Vt[64][72];
  __shared__ unsigned short Pl[4][64][72];

  // Q fragments (B operand): lane holds Q[q = w*64+fnq*16+lc][c = ks*32+lg*8 ..+8]
  u32x4 qf[4][2];
  {
    const unsigned short* qb = qbf + ((size_t)(n * QQ + w * 64 + lc)) * DD + h * CC + lg * 8;
    #pragma unroll
    for (int fnq = 0; fnq < 4; ++fnq)
      #pragma unroll
      for (int ks = 0; ks < 2; ++ks)
        qf[fnq][ks] = *(const u32x4*)(qb + (size_t)fnq * 16 * DD + ks * 32);
  }
  // te preloads for staging segments
  float tk[16];
  {
    const float* tkp = tek + (size_t)t * DD + h * CC + (tid & 3) * 16;
    #pragma unroll
    for (int i = 0; i < 16; ++i) tk[i] = tkp[i];
  }
  float tv8[8];
  {
    const float* tvp = tev + (size_t)t * DD + h * CC + (tid >> 5) * 8;
    #pragma unroll
    for (int i = 0; i < 8; ++i) tv8[i] = tvp[i];
  }

  f32x4 oacc[4][4] = {};   // [fmc(c)][fnq(q)]
  float mrun[4], lrun[4];
  #pragma unroll
  for (int i = 0; i < 4; ++i) { mrun[i] = -1e30f; lrun[i] = 0.f; }

  const size_t krow0 = (((size_t)(n * TT + t) * LL + 1) * HH + h) * CC;
  const float* mbase = mask + (size_t)(w * 64) * QQ;

  for (int c0 = 0; c0 < QQ; c0 += 64) {
    __syncthreads();
    {   // stage K (+te_k) row-major [key][c], padded
      const int kr = tid >> 2, cs = (tid & 3) * 16;
      const float* kp = ak + krow0 + (size_t)(c0 + kr) * (HH * CC) + cs;
      const float4 k0 = ld4(kp), k1 = ld4(kp + 4), k2 = ld4(kp + 8), k3 = ld4(kp + 12);
      float kv[16] = {k0.x,k0.y,k0.z,k0.w,k1.x,k1.y,k1.z,k1.w,
                      k2.x,k2.y,k2.z,k2.w,k3.x,k3.y,k3.z,k3.w};
      #pragma unroll
      for (int i = 0; i < 16; ++i) kv[i] += tk[i];
      u32x4 pa; pa.x = pk2(kv[0],kv[1]);  pa.y = pk2(kv[2],kv[3]);
      pa.z = pk2(kv[4],kv[5]);  pa.w = pk2(kv[6],kv[7]);
      u32x4 pb; pb.x = pk2(kv[8],kv[9]);  pb.y = pk2(kv[10],kv[11]);
      pb.z = pk2(kv[12],kv[13]); pb.w = pk2(kv[14],kv[15]);
      *(u32x4*)&Ks[kr][cs] = pa;
      *(u32x4*)&Ks[kr][cs + 8] = pb;
    }
    {   // stage V transposed (+te_v): Vt[c][key], 2 keys per b32 write
      const int kp2 = tid & 31, ch = tid >> 5;
      const float* vr0 = av + krow0 + (size_t)(c0 + 2 * kp2) * (HH * CC) + ch * 8;
      const float* vr1 = vr0 + HH * CC;
      const float4 a0 = ld4(vr0), a1 = ld4(vr0 + 4);
      const float4 b0 = ld4(vr1), b1 = ld4(vr1 + 4);
      const float va[8] = {a0.x,a0.y,a0.z,a0.w,a1.x,a1.y,a1.z,a1.w};
      const float vb[8] = {b0.x,b0.y,b0.z,b0.w,b1.x,b1.y,b1.z,b1.w};
      #pragma unroll
      for (int i = 0; i < 8; ++i)
        *(unsigned int*)&Vt[ch * 8 + i][2 * kp2] = pk2(va[i] + tv8[i], vb[i] + tv8[i]);
    }
    __syncthreads();

    // S^T = K @ Q : sf[fmk(key)][fnq(q)]
    f32x4 sf[4][4] = {};
    #pragma unroll
    for (int ks = 0; ks < 2; ++ks) {
      u32x4 kf[4];
      #pragma unroll
      for (int fmk = 0; fmk < 4; ++fmk)
        kf[fmk] = *(const u32x4*)&Ks[fmk * 16 + lc][ks * 32 + lg * 8];
      #pragma unroll
      for (int fmk = 0; fmk < 4; ++fmk)
        #pragma unroll
        for (int fnq = 0; fnq < 4; ++fnq)
          mfma16(sf[fmk][fnq], kf[fmk], qf[fnq][ks]);
    }

    // mask + online softmax per q (fnq); write P (bf16) to per-wave LDS
    #pragma unroll
    for (int fnq = 0; fnq < 4; ++fnq) {
      const float* mrow = mbase + (size_t)(fnq * 16 + lc) * QQ + c0 + lg * 4;
      f32x4 mk[4];
      #pragma unroll
      for (int fmk = 0; fmk < 4; ++fmk) mk[fmk] = *(const f32x4*)(mrow + fmk * 16);
      #pragma unroll
      for (int fmk = 0; fmk < 4; ++fmk) sf[fmk][fnq] += mk[fmk];
      float mx = -1e30f;
      #pragma unroll
      for (int fmk = 0; fmk < 4; ++fmk) {
        mx = fmaxf(mx, fmaxf(fmaxf(sf[fmk][fnq][0], sf[fmk][fnq][1]),
                             fmaxf(sf[fmk][fnq][2], sf[fmk][fnq][3])));
      }
      mx = fmaxf(mx, __shfl_xor(mx, 16));
      mx = fmaxf(mx, __shfl_xor(mx, 32));
      const float mnew = fmaxf(mrun[fnq], mx);
      const float corr = __expf(mrun[fnq] - mnew);
      mrun[fnq] = mnew;
      float ls = 0.f;
      #pragma unroll
      for (int fmk = 0; fmk < 4; ++fmk) {
        const float p0 = __expf(sf[fmk][fnq][0] - mnew);
        const float p1 = __expf(sf[fmk][fnq][1] - mnew);
        const float p2 = __expf(sf[fmk][fnq][2] - mnew);
        const float p3 = __expf(sf[fmk][fnq][3] - mnew);
        ls += (p0 + p1) + (p2 + p3);
        u32x2 pw; pw.x = pk2(p0, p1); pw.y = pk2(p2, p3);
        *(u32x2*)&Pl[w][fnq * 16 + lc][fmk * 16 + lg * 4] = pw;
      }
      ls += __shfl_xor(ls, 16);
      ls += __shfl_xor(ls, 32);
      lrun[fnq] = lrun[fnq] * corr + ls;
      #pragma unroll
      for (int fmc = 0; fmc < 4; ++fmc) oacc[fmc][fnq] *= corr;
    }

    // PV: O^T += Vt @ P   (A = Vt[c][key], B = P[q][key] read k-contiguous)
    #pragma unroll
    for (int ks = 0; ks < 2; ++ks) {
      u32x4 vf[4], pf[4];
      #pragma unroll
      for (int fmc = 0; fmc < 4; ++fmc)
        vf[fmc] = *(const u32x4*)&Vt[fmc * 16 + lc][ks * 32 + lg * 8];
      #pragma unroll
      for (int fnq = 0; fnq < 4; ++fnq)
        pf[fnq] = *(const u32x4*)&Pl[w][fnq * 16 + lc][ks * 32 + lg * 8];
      #pragma unroll
      for (int fmc = 0; fmc < 4; ++fmc)
        #pragma unroll
        for (int fnq = 0; fnq < 4; ++fnq)
          mfma16(oacc[fmc][fnq], vf[fmc], pf[fnq]);
    }
  }

  // epilogue: O^T frag -> smix[n][t][q][h][c], 4 consecutive c per store
  #pragma unroll
  for (int fnq = 0; fnq < 4; ++fnq) {
    const float inv = 1.f / lrun[fnq];
    const int qg = w * 64 + fnq * 16 + lc;
    float* op = smix + ((((size_t)(n * TT + t) * QQ + qg) * HH + h) * CC + lg * 4);
    #pragma unroll
    for (int fmc = 0; fmc < 4; ++fmc) {
      f32x4 o = oacc[fmc][fnq] * inv;
      *(f32x4*)(op + fmc * 16) = o;
    }
  }
}

// -------------------------------------------- conv3+mean_t combine ----
__global__ __launch_bounds__(256) void combine_kernel(
    const float* __restrict__ smix, const float* __restrict__ cw,
    const float* __restrict__ cb, float* __restrict__ smm) {
  const int nq = blockIdx.x;
  const int d = threadIdx.x * 4;
  const int n = nq >> 8, q = nq & 255;
  const float* base = smix + ((size_t)n * TT * QQ + q) * DD + d;
  float4 S = make_float4(0.f, 0.f, 0.f, 0.f);
  float4 x0 = make_float4(0.f, 0.f, 0.f, 0.f), x7 = x0;
  #pragma unroll
  for (int t = 0; t < TT; ++t) {
    const float4 v = *(const float4*)(base + (size_t)t * QQ * DD);
    if (t == 0) x0 = v;
    if (t == 7) x7 = v;
    S.x += v.x; S.y += v.y; S.z += v.z; S.w += v.w;
  }
  const float Sa[4] = {S.x, S.y, S.z, S.w};
  const float X0[4] = {x0.x, x0.y, x0.z, x0.w};
  const float X7[4] = {x7.x, x7.y, x7.z, x7.w};
  float o[4];
  #pragma unroll
  for (int i = 0; i < 4; ++i) {
    const int chn = d + i;
    const float w0 = cw[chn*3+0], w1 = cw[chn*3+1], w2 = cw[chn*3+2];
    o[i] = ((1.f + w0 + w1 + w2) * Sa[i] - w0 * X7[i] - w2 * X0[i]) * 0.125f + cb[chn];
  }
  *(float4*)(smm + (size_t)nq * DD + d) = make_float4(o[0], o[1], o[2], o[3]);
}

// ------------------------------------------------------------ launch ----
extern "C" void kernel_launch(void* const* d_in, const int* in_sizes, int n_in,
                              void* d_out, int out_size, void* d_ws, size_t ws_size,
                              hipStream_t stream) {
  const float* attrs_k = (const float*)d_in[0];
  const float* attrs_v = (const float*)d_in[1];
  const float* s       = (const float*)d_in[2];
  const float* te      = (const float*)d_in[3];
  const float* pmask   = (const float*)d_in[4];
  const float* ln1_w   = (const float*)d_in[5];
  const float* ln1_b   = (const float*)d_in[6];
  const float* inW     = (const float*)d_in[7];
  const float* inB     = (const float*)d_in[8];
  const float* outW    = (const float*)d_in[9];
  const float* outB    = (const float*)d_in[10];
  const float* ln2_w   = (const float*)d_in[11];
  const float* ln2_b   = (const float*)d_in[12];
  const float* fcW     = (const float*)d_in[13];
  const float* fcB     = (const float*)d_in[14];
  const float* pjW     = (const float*)d_in[15];
  const float* pjB     = (const float*)d_in[16];
  const float* sylnW   = (const float*)d_in[17];
  const float* sylnB   = (const float*)d_in[18];
  const float* syl1    = (const float*)d_in[19];
  const float* syl2    = (const float*)d_in[20];
  const float* telnW   = (const float*)d_in[21];
  const float* telnB   = (const float*)d_in[22];
  const float* tel1    = (const float*)d_in[23];
  const float* tel2    = (const float*)d_in[24];
  const float* tconvW  = (const float*)d_in[25];
  const float* tconvB  = (const float*)d_in[26];

  float* ws    = (float*)d_ws;
  float* f_te  = ws;                  //   8192
  float* f_tek = ws + 8192;           //   8192
  float* f_tev = ws + 16384;          //   8192
  float* f_mid = ws + 24576;          // 262144
  float* bufA  = ws + 524288;         // 2097152: LN outputs
  float* bufB  = bufA + 2097152;      // 2097152: _s, later smm
  float* bufC  = bufB + 2097152;      // 2097152: s_q bf16 lives here
  float* smix  = bufC + 2097152;      // 16777216 f32
  float* s1    = smix + 8388608;      // 2097152 (smix dead by then)
  unsigned short* qbf  = (unsigned short*)bufC;
  unsigned short* hmid = (unsigned short*)smix;  // 8.4M bf16 (smix dead)
  float* outp  = (float*)d_out;

  adaptor_te_kernel<<<TT, 256, 0, stream>>>(te, telnW, telnB, tel1, tel2, f_te);
  te_kv_kernel<<<8, 256, 0, stream>>>(f_te, inW, inB, f_tek, f_tev);
  ln_kernel<<<NQ, 256, 0, stream>>>(s, sylnW, sylnB, bufA);
  gemm_f32<0><<<dim3(1, 16), 256, 0, stream>>>(bufA, syl1, nullptr, nullptr, f_mid, NQ, 128, DD);
  gemm_f32<4><<<dim3(8, 16), 256, 0, stream>>>(f_mid, syl2, nullptr, s, bufB, NQ, DD, 128);
  ln_kernel<<<NQ, 256, 0, stream>>>(bufB, ln1_w, ln1_b, bufA);
  // s_q = (x @ Wq^T + bq) * 0.125 -> bf16
  gemm_mfma<1, 0><<<dim3(8, 16), 256, 0, stream>>>(bufA, inW, inB, nullptr, qbf, NQ, DD, DD);
  attn_mfma<<<dim3(HH, TT, NN), 256, 0, stream>>>(attrs_k, attrs_v, qbf, f_tek, f_tev, pmask, smix);
  combine_kernel<<<NQ, 256, 0, stream>>>(smix, tconvW, tconvB, bufB);
  // s1 = s + smm @ outW^T + outB
  gemm_mfma<3, 0><<<dim3(8, 16), 256, 0, stream>>>(bufB, outW, outB, s, s1, NQ, DD, DD);
  ln_kernel<<<NQ, 256, 0, stream>>>(s1, ln2_w, ln2_b, bufA);
  // hmid = qgelu(x2 @ fcW^T + fcB) -> bf16
  gemm_mfma<2, 0><<<dim3(32, 16), 256, 0, stream>>>(bufA, fcW, fcB, nullptr, hmid, NQ, 4 * DD, DD);
  // out = s1 + hmid @ pjW^T + pjB
  gemm_mfma<3, 1><<<dim3(8, 16), 256, 0, stream>>>(hmid, pjW, pjB, s1, outp, NQ, DD, 4 * DD);
}

// Round 3
// 427.345 us; speedup vs baseline: 4.7597x; 1.6804x over previous
//
#include <hip/hip_runtime.h>

#define NN 8
#define TT 8
#define LL 257
#define HH 16
#define CC 64
#define DD 1024
#define QQ 256
#define NQ (NN*QQ)   // 2048

typedef __attribute__((ext_vector_type(4))) float f32x4;
typedef __attribute__((ext_vector_type(4))) unsigned int u32x4;
typedef __attribute__((ext_vector_type(2))) unsigned int u32x2;

static __device__ __forceinline__ float4 ld4(const float* p) { return *(const float4*)p; }

static __device__ __forceinline__ void mfma16(f32x4& d, u32x4 a, u32x4 b) {
  asm("v_mfma_f32_16x16x32_bf16 %0, %1, %2, %0" : "+v"(d) : "v"(a), "v"(b));
}

static __device__ __forceinline__ unsigned int f2bf(float x) {
  unsigned int u = __float_as_uint(x);
  return (u + 0x7fffu + ((u >> 16) & 1u)) >> 16;
}
static __device__ __forceinline__ unsigned int pk2(float lo, float hi) {
  return f2bf(lo) | (f2bf(hi) << 16);
}
static __device__ __forceinline__ float bf2f(unsigned int u) {
  return __uint_as_float(u << 16);
}

typedef __attribute__((address_space(3))) unsigned char lds_t;
typedef const __attribute__((address_space(1))) unsigned char glb_t;
static __device__ __forceinline__ void gld16(const void* g, void* l) {
  __builtin_amdgcn_global_load_lds((glb_t*)g, (lds_t*)l, 16, 0, 0);
}

// ----------------------------------------------------- f32 -> bf16 ----
__global__ __launch_bounds__(256) void cvt_bf16_kernel(const float* __restrict__ in,
    unsigned short* __restrict__ out, int n4) {
  const int i = blockIdx.x * 256 + threadIdx.x;
  if (i < n4) {
    const float4 v = ld4(in + (size_t)i * 4);
    u32x2 p; p.x = pk2(v.x, v.y); p.y = pk2(v.z, v.w);
    *(u32x2*)(out + (size_t)i * 4) = p;
  }
}

// ------------------------------------------------- LN (bf16 output) ----
__global__ __launch_bounds__(256) void ln_bf_kernel(const float* __restrict__ in,
    const float* __restrict__ w, const float* __restrict__ b, unsigned short* __restrict__ out) {
  __shared__ float red[16];
  const int tid = threadIdx.x;
  const size_t row = blockIdx.x;
  const float4 v = ((const float4*)(in + row * DD))[tid];
  float s  = v.x + v.y + v.z + v.w;
  float ss = v.x*v.x + v.y*v.y + v.z*v.z + v.w*v.w;
  #pragma unroll
  for (int off = 32; off; off >>= 1) { s += __shfl_xor(s, off); ss += __shfl_xor(ss, off); }
  if ((tid & 63) == 0) { red[tid >> 6] = s; red[8 + (tid >> 6)] = ss; }
  __syncthreads();
  s  = red[0] + red[1] + red[2] + red[3];
  ss = red[8] + red[9] + red[10] + red[11];
  const float mean = s * (1.f / DD);
  const float var  = ss * (1.f / DD) - mean * mean;
  const float inv  = rsqrtf(var + 1e-5f);
  const float4 wv = ((const float4*)w)[tid];
  const float4 bv = ((const float4*)b)[tid];
  float o0 = (v.x - mean) * inv * wv.x + bv.x;
  float o1 = (v.y - mean) * inv * wv.y + bv.y;
  float o2 = (v.z - mean) * inv * wv.z + bv.z;
  float o3 = (v.w - mean) * inv * wv.w + bv.w;
  u32x2 p; p.x = pk2(o0, o1); p.y = pk2(o2, o3);
  *(u32x2*)(out + row * DD + tid * 4) = p;
}

// ------------------------------------------------------- te adaptor ----
__global__ __launch_bounds__(256) void adaptor_te_kernel(
    const float* __restrict__ te, const float* __restrict__ lnw, const float* __restrict__ lnb,
    const float* __restrict__ l1, const float* __restrict__ l2, float* __restrict__ out) {
  __shared__ float hsh[1024];
  __shared__ float midsh[128];
  __shared__ float red[16];
  const int t = blockIdx.x, tid = threadIdx.x;
  const float4 v = ((const float4*)(te + (size_t)t * DD))[tid];
  float s  = v.x + v.y + v.z + v.w;
  float ss = v.x*v.x + v.y*v.y + v.z*v.z + v.w*v.w;
  #pragma unroll
  for (int off = 32; off; off >>= 1) { s += __shfl_xor(s, off); ss += __shfl_xor(ss, off); }
  if ((tid & 63) == 0) { red[tid >> 6] = s; red[8 + (tid >> 6)] = ss; }
  __syncthreads();
  s  = red[0] + red[1] + red[2] + red[3];
  ss = red[8] + red[9] + red[10] + red[11];
  const float mean = s * (1.f / DD), var = ss * (1.f / DD) - mean * mean;
  const float inv = rsqrtf(var + 1e-5f);
  const float4 w4 = ((const float4*)lnw)[tid], b4 = ((const float4*)lnb)[tid];
  float4 hv;
  hv.x = (v.x - mean) * inv * w4.x + b4.x;
  hv.y = (v.y - mean) * inv * w4.y + b4.y;
  hv.z = (v.z - mean) * inv * w4.z + b4.z;
  hv.w = (v.w - mean) * inv * w4.w + b4.w;
  ((float4*)hsh)[tid] = hv;
  __syncthreads();
  const int j = tid >> 1, p = tid & 1;
  const float* l1r = l1 + (size_t)j * DD + p * 512;
  const float* hp  = hsh + p * 512;
  float acc = 0.f;
  for (int i = 0; i < 512; i += 4) {
    const float4 a  = ld4(l1r + i);
    const float4 hh = ld4(hp + i);
    acc += a.x*hh.x + a.y*hh.y + a.z*hh.z + a.w*hh.w;
  }
  acc += __shfl_xor(acc, 1);
  if (p == 0) midsh[j] = acc;
  __syncthreads();
  float o4[4];
  #pragma unroll
  for (int c = 0; c < 4; ++c) {
    const int dd = tid * 4 + c;
    const float* l2r = l2 + (size_t)dd * 128;
    float a = 0.f;
    for (int jj = 0; jj < 128; jj += 4) {
      const float4 mm = ld4(midsh + jj);
      const float4 ww = ld4(l2r + jj);
      a += mm.x*ww.x + mm.y*ww.y + mm.z*ww.z + mm.w*ww.w;
    }
    o4[c] = a;
  }
  *(float4*)(out + (size_t)t * DD + tid * 4) =
      make_float4(o4[0] + v.x, o4[1] + v.y, o4[2] + v.z, o4[3] + v.w);
}

// ----------------------------------------------------------- te k/v ----
__global__ __launch_bounds__(256) void te_kv_kernel(
    const float* __restrict__ _te, const float* __restrict__ W, const float* __restrict__ bias,
    float* __restrict__ tek, float* __restrict__ tev) {
  __shared__ float tes[8 * 1024];
  const int tid = threadIdx.x;
  for (int i = tid; i < 2048; i += 256) ((float4*)tes)[i] = ((const float4*)_te)[i];
  __syncthreads();
  const int idx = blockIdx.x * 256 + tid;   // 0..2047
  const float* wr = W + (size_t)(1024 + idx) * DD;
  float acc[8] = {0.f,0.f,0.f,0.f,0.f,0.f,0.f,0.f};
  for (int kk = 0; kk < DD; kk += 4) {
    const float4 w4 = ld4(wr + kk);
    #pragma unroll
    for (int t = 0; t < 8; ++t) {
      const float4 h4 = ld4(tes + t * 1024 + kk);
      acc[t] += w4.x*h4.x + w4.y*h4.y + w4.z*h4.z + w4.w*h4.w;
    }
  }
  const float bv = bias[1024 + idx];
  #pragma unroll
  for (int t = 0; t < 8; ++t) {
    if (idx < 1024) tek[(size_t)t * DD + idx] = acc[t] + bv;
    else            tev[(size_t)t * DD + (idx - 1024)] = acc[t] + bv;
  }
}

// ------------------------------------------- bf16 MFMA GEMM (64x128) ----
// C[M,N] = epi(A[M,K] @ W[N,K]^T), A/W bf16, 2-phase double-buffered
// global_load_lds staging. EPI: 0 ->bf16 | 1 (x+b)*0.125 ->bf16 |
// 2 qgelu(x+b) ->bf16 | 3 x+b+res ->f32 | 4 x+res ->f32
template<int EPI>
__global__ __launch_bounds__(256) void gemm_bf(
    const unsigned short* __restrict__ A, const unsigned short* __restrict__ W,
    const float* __restrict__ bias, const float* __restrict__ res,
    void* __restrict__ Cv, int M, int N, int K) {
  __shared__ unsigned short As[2][64 * 64];
  __shared__ unsigned short Bs[2][128 * 64];
  const int tid = threadIdx.x, w = tid >> 6, l = tid & 63;
  const int lc = l & 15, lg = l >> 4;
  const int m0 = blockIdx.y * 64, n0 = blockIdx.x * 128;
  const int wm = (w >> 1) * 32, wn = (w & 1) * 64;
  const int rrow = tid >> 3, seg8 = (tid & 7) * 8;

  f32x4 acc[2][4] = {};

  auto stagef = [&](int kt, int b) {
    const int k0 = kt * 64;
    #pragma unroll
    for (int r = 0; r < 2; ++r)
      gld16(A + (size_t)(m0 + r * 32 + rrow) * K + k0 + seg8, &As[b][r * 2048 + w * 512]);
    #pragma unroll
    for (int r = 0; r < 4; ++r)
      gld16(W + (size_t)(n0 + r * 32 + rrow) * K + k0 + seg8, &Bs[b][r * 2048 + w * 512]);
  };
  auto computef = [&](int b) {
    #pragma unroll
    for (int ks = 0; ks < 2; ++ks) {
      u32x4 af[2], bfr[4];
      #pragma unroll
      for (int i = 0; i < 2; ++i)
        af[i] = *(const u32x4*)&As[b][(wm + i * 16 + lc) * 64 + ks * 32 + lg * 8];
      #pragma unroll
      for (int j = 0; j < 4; ++j)
        bfr[j] = *(const u32x4*)&Bs[b][(wn + j * 16 + lc) * 64 + ks * 32 + lg * 8];
      #pragma unroll
      for (int i = 0; i < 2; ++i)
        #pragma unroll
        for (int j = 0; j < 4; ++j)
          mfma16(acc[i][j], af[i], bfr[j]);
    }
  };

  const int NT = K >> 6;
  stagef(0, 0);
  asm volatile("s_waitcnt vmcnt(0)" ::: "memory");
  __builtin_amdgcn_s_barrier();
  int cur = 0;
  for (int kt = 0; kt < NT - 1; ++kt) {
    stagef(kt + 1, cur ^ 1);
    computef(cur);
    asm volatile("s_waitcnt vmcnt(0)" ::: "memory");
    __builtin_amdgcn_s_barrier();
    cur ^= 1;
  }
  computef(cur);

  float bias4[4];
  if (EPI == 1 || EPI == 2 || EPI == 3) {
    #pragma unroll
    for (int j = 0; j < 4; ++j) bias4[j] = bias[n0 + wn + j * 16 + lc];
  }
  #pragma unroll
  for (int i = 0; i < 2; ++i) {
    #pragma unroll
    for (int j = 0; j < 4; ++j) {
      const int col = n0 + wn + j * 16 + lc;
      #pragma unroll
      for (int r = 0; r < 4; ++r) {
        const int row = m0 + wm + i * 16 + lg * 4 + r;
        float x = acc[i][j][r];
        if (EPI == 0) {
          ((unsigned short*)Cv)[(size_t)row * N + col] = (unsigned short)f2bf(x);
        } else if (EPI == 1) {
          x = (x + bias4[j]) * 0.125f;
          ((unsigned short*)Cv)[(size_t)row * N + col] = (unsigned short)f2bf(x);
        } else if (EPI == 2) {
          x += bias4[j];
          x = x / (1.f + __expf(-1.702f * x));
          ((unsigned short*)Cv)[(size_t)row * N + col] = (unsigned short)f2bf(x);
        } else if (EPI == 3) {
          x += bias4[j] + res[(size_t)row * N + col];
          ((float*)Cv)[(size_t)row * N + col] = x;
        } else {
          x += res[(size_t)row * N + col];
          ((float*)Cv)[(size_t)row * N + col] = x;
        }
      }
    }
  }
}

// -------------------------------------------------- MFMA attention ----
__global__ __launch_bounds__(256, 2) void attn_mfma(
    const float* __restrict__ ak, const float* __restrict__ av,
    const unsigned short* __restrict__ qbf,
    const float* __restrict__ tek, const float* __restrict__ tev,
    const float* __restrict__ mask, unsigned short* __restrict__ smix) {
  const int h = blockIdx.x, t = blockIdx.y, n = blockIdx.z;
  const int tid = threadIdx.x, w = tid >> 6, l = tid & 63;
  const int lc = l & 15, lg = l >> 4;
  __shared__ unsigned short Ks[64][72];
  __shared__ unsigned short Vt[64][72];
  __shared__ unsigned short Pl[4][64][72];

  u32x4 qf[4][2];
  {
    const unsigned short* qb = qbf + ((size_t)(n * QQ + w * 64 + lc)) * DD + h * CC + lg * 8;
    #pragma unroll
    for (int fnq = 0; fnq < 4; ++fnq)
      #pragma unroll
      for (int ks = 0; ks < 2; ++ks)
        qf[fnq][ks] = *(const u32x4*)(qb + (size_t)fnq * 16 * DD + ks * 32);
  }
  float tk[16];
  {
    const float* tkp = tek + (size_t)t * DD + h * CC + (tid & 3) * 16;
    #pragma unroll
    for (int i = 0; i < 16; ++i) tk[i] = tkp[i];
  }
  float tv8[8];
  {
    const float* tvp = tev + (size_t)t * DD + h * CC + (tid >> 5) * 8;
    #pragma unroll
    for (int i = 0; i < 8; ++i) tv8[i] = tvp[i];
  }

  f32x4 oacc[4][4] = {};
  float mrun[4], lrun[4];
  #pragma unroll
  for (int i = 0; i < 4; ++i) { mrun[i] = -1e30f; lrun[i] = 0.f; }

  const size_t krow0 = (((size_t)(n * TT + t) * LL + 1) * HH + h) * CC;
  const float* mbase = mask + (size_t)(w * 64) * QQ;

  for (int c0 = 0; c0 < QQ; c0 += 64) {
    __syncthreads();
    {
      const int kr = tid >> 2, cs = (tid & 3) * 16;
      const float* kp = ak + krow0 + (size_t)(c0 + kr) * (HH * CC) + cs;
      const float4 k0 = ld4(kp), k1 = ld4(kp + 4), k2 = ld4(kp + 8), k3 = ld4(kp + 12);
      float kv[16] = {k0.x,k0.y,k0.z,k0.w,k1.x,k1.y,k1.z,k1.w,
                      k2.x,k2.y,k2.z,k2.w,k3.x,k3.y,k3.z,k3.w};
      #pragma unroll
      for (int i = 0; i < 16; ++i) kv[i] += tk[i];
      u32x4 pa; pa.x = pk2(kv[0],kv[1]);  pa.y = pk2(kv[2],kv[3]);
      pa.z = pk2(kv[4],kv[5]);  pa.w = pk2(kv[6],kv[7]);
      u32x4 pb; pb.x = pk2(kv[8],kv[9]);  pb.y = pk2(kv[10],kv[11]);
      pb.z = pk2(kv[12],kv[13]); pb.w = pk2(kv[14],kv[15]);
      *(u32x4*)&Ks[kr][cs] = pa;
      *(u32x4*)&Ks[kr][cs + 8] = pb;
    }
    {
      const int kp2 = tid & 31, ch = tid >> 5;
      const float* vr0 = av + krow0 + (size_t)(c0 + 2 * kp2) * (HH * CC) + ch * 8;
      const float* vr1 = vr0 + HH * CC;
      const float4 a0 = ld4(vr0), a1 = ld4(vr0 + 4);
      const float4 b0 = ld4(vr1), b1 = ld4(vr1 + 4);
      const float va[8] = {a0.x,a0.y,a0.z,a0.w,a1.x,a1.y,a1.z,a1.w};
      const float vb[8] = {b0.x,b0.y,b0.z,b0.w,b1.x,b1.y,b1.z,b1.w};
      #pragma unroll
      for (int i = 0; i < 8; ++i)
        *(unsigned int*)&Vt[ch * 8 + i][2 * kp2] = pk2(va[i] + tv8[i], vb[i] + tv8[i]);
    }
    __syncthreads();

    f32x4 sf[4][4] = {};
    #pragma unroll
    for (int ks = 0; ks < 2; ++ks) {
      u32x4 kf[4];
      #pragma unroll
      for (int fmk = 0; fmk < 4; ++fmk)
        kf[fmk] = *(const u32x4*)&Ks[fmk * 16 + lc][ks * 32 + lg * 8];
      #pragma unroll
      for (int fmk = 0; fmk < 4; ++fmk)
        #pragma unroll
        for (int fnq = 0; fnq < 4; ++fnq)
          mfma16(sf[fmk][fnq], kf[fmk], qf[fnq][ks]);
    }

    #pragma unroll
    for (int fnq = 0; fnq < 4; ++fnq) {
      const float* mrow = mbase + (size_t)(fnq * 16 + lc) * QQ + c0 + lg * 4;
      f32x4 mk[4];
      #pragma unroll
      for (int fmk = 0; fmk < 4; ++fmk) mk[fmk] = *(const f32x4*)(mrow + fmk * 16);
      #pragma unroll
      for (int fmk = 0; fmk < 4; ++fmk) sf[fmk][fnq] += mk[fmk];
      float mx = -1e30f;
      #pragma unroll
      for (int fmk = 0; fmk < 4; ++fmk) {
        mx = fmaxf(mx, fmaxf(fmaxf(sf[fmk][fnq][0], sf[fmk][fnq][1]),
                             fmaxf(sf[fmk][fnq][2], sf[fmk][fnq][3])));
      }
      mx = fmaxf(mx, __shfl_xor(mx, 16));
      mx = fmaxf(mx, __shfl_xor(mx, 32));
      const float mnew = fmaxf(mrun[fnq], mx);
      const float corr = __expf(mrun[fnq] - mnew);
      mrun[fnq] = mnew;
      float ls = 0.f;
      #pragma unroll
      for (int fmk = 0; fmk < 4; ++fmk) {
        const float p0 = __expf(sf[fmk][fnq][0] - mnew);
        const float p1 = __expf(sf[fmk][fnq][1] - mnew);
        const float p2 = __expf(sf[fmk][fnq][2] - mnew);
        const float p3 = __expf(sf[fmk][fnq][3] - mnew);
        ls += (p0 + p1) + (p2 + p3);
        u32x2 pw; pw.x = pk2(p0, p1); pw.y = pk2(p2, p3);
        *(u32x2*)&Pl[w][fnq * 16 + lc][fmk * 16 + lg * 4] = pw;
      }
      ls += __shfl_xor(ls, 16);
      ls += __shfl_xor(ls, 32);
      lrun[fnq] = lrun[fnq] * corr + ls;
      #pragma unroll
      for (int fmc = 0; fmc < 4; ++fmc) oacc[fmc][fnq] *= corr;
    }

    #pragma unroll
    for (int ks = 0; ks < 2; ++ks) {
      u32x4 vf[4], pf[4];
      #pragma unroll
      for (int fmc = 0; fmc < 4; ++fmc)
        vf[fmc] = *(const u32x4*)&Vt[fmc * 16 + lc][ks * 32 + lg * 8];
      #pragma unroll
      for (int fnq = 0; fnq < 4; ++fnq)
        pf[fnq] = *(const u32x4*)&Pl[w][fnq * 16 + lc][ks * 32 + lg * 8];
      #pragma unroll
      for (int fmc = 0; fmc < 4; ++fmc)
        #pragma unroll
        for (int fnq = 0; fnq < 4; ++fnq)
          mfma16(oacc[fmc][fnq], vf[fmc], pf[fnq]);
    }
  }

  #pragma unroll
  for (int fnq = 0; fnq < 4; ++fnq) {
    const float inv = 1.f / lrun[fnq];
    const int qg = w * 64 + fnq * 16 + lc;
    unsigned short* op = smix + ((((size_t)(n * TT + t) * QQ + qg) * HH + h) * CC + lg * 4);
    #pragma unroll
    for (int fmc = 0; fmc < 4; ++fmc) {
      const f32x4 o = oacc[fmc][fnq] * inv;
      u32x2 p; p.x = pk2(o[0], o[1]); p.y = pk2(o[2], o[3]);
      *(u32x2*)(op + fmc * 16) = p;
    }
  }
}

// -------------------------------------------- conv3+mean_t combine ----
__global__ __launch_bounds__(256) void combine_kernel(
    const unsigned short* __restrict__ smix, const float* __restrict__ cw,
    const float* __restrict__ cb, unsigned short* __restrict__ smm) {
  const int nq = blockIdx.x;
  const int d = threadIdx.x * 4;
  const int n = nq >> 8, q = nq & 255;
  const unsigned short* base = smix + ((size_t)n * TT * QQ + q) * DD + d;
  float S[4] = {0.f, 0.f, 0.f, 0.f};
  float X0[4], X7[4];
  #pragma unroll
  for (int t = 0; t < TT; ++t) {
    const u32x2 pv = *(const u32x2*)(base + (size_t)t * QQ * DD);
    const float v[4] = {bf2f(pv.x & 0xffffu), bf2f(pv.x >> 16),
                        bf2f(pv.y & 0xffffu), bf2f(pv.y >> 16)};
    if (t == 0) { X0[0]=v[0]; X0[1]=v[1]; X0[2]=v[2]; X0[3]=v[3]; }
    if (t == 7) { X7[0]=v[0]; X7[1]=v[1]; X7[2]=v[2]; X7[3]=v[3]; }
    #pragma unroll
    for (int i = 0; i < 4; ++i) S[i] += v[i];
  }
  float o[4];
  #pragma unroll
  for (int i = 0; i < 4; ++i) {
    const int chn = d + i;
    const float w0 = cw[chn*3+0], w1 = cw[chn*3+1], w2 = cw[chn*3+2];
    o[i] = ((1.f + w0 + w1 + w2) * S[i] - w0 * X7[i] - w2 * X0[i]) * 0.125f + cb[chn];
  }
  u32x2 p; p.x = pk2(o[0], o[1]); p.y = pk2(o[2], o[3]);
  *(u32x2*)(smm + (size_t)nq * DD + d) = p;
}

// ------------------------------------------------------------ launch ----
extern "C" void kernel_launch(void* const* d_in, const int* in_sizes, int n_in,
                              void* d_out, int out_size, void* d_ws, size_t ws_size,
                              hipStream_t stream) {
  const float* attrs_k = (const float*)d_in[0];
  const float* attrs_v = (const float*)d_in[1];
  const float* s       = (const float*)d_in[2];
  const float* te      = (const float*)d_in[3];
  const float* pmask   = (const float*)d_in[4];
  const float* ln1_w   = (const float*)d_in[5];
  const float* ln1_b   = (const float*)d_in[6];
  const float* inW     = (const float*)d_in[7];
  const float* inB     = (const float*)d_in[8];
  const float* outW    = (const float*)d_in[9];
  const float* outB    = (const float*)d_in[10];
  const float* ln2_w   = (const float*)d_in[11];
  const float* ln2_b   = (const float*)d_in[12];
  const float* fcW     = (const float*)d_in[13];
  const float* fcB     = (const float*)d_in[14];
  const float* pjW     = (const float*)d_in[15];
  const float* pjB     = (const float*)d_in[16];
  const float* sylnW   = (const float*)d_in[17];
  const float* sylnB   = (const float*)d_in[18];
  const float* syl1    = (const float*)d_in[19];
  const float* syl2    = (const float*)d_in[20];
  const float* telnW   = (const float*)d_in[21];
  const float* telnB   = (const float*)d_in[22];
  const float* tel1    = (const float*)d_in[23];
  const float* tel2    = (const float*)d_in[24];
  const float* tconvW  = (const float*)d_in[25];
  const float* tconvB  = (const float*)d_in[26];

  float* ws = (float*)d_ws;
  float*          f_te   = ws;                                  // 8192
  float*          f_tek  = ws + 8192;                           // 8192
  float*          f_tev  = ws + 16384;                          // 8192
  unsigned short* syl1b  = (unsigned short*)(ws + 32768);       // 65536 f
  unsigned short* syl2b  = (unsigned short*)(ws + 98304);       // 65536 f
  unsigned short* midb   = (unsigned short*)(ws + 163840);      // 131072 f
  unsigned short* bufAb  = (unsigned short*)(ws + 327680);      // 524288 f (LN outs)
  unsigned short* qbf    = (unsigned short*)(ws + 851968);      // 524288 f
  unsigned short* smmb   = (unsigned short*)(ws + 1376256);     // 524288 f
  unsigned short* wqb    = (unsigned short*)(ws + 1900544);     // 524288 f
  unsigned short* outwb  = (unsigned short*)(ws + 2424832);     // 524288 f
  unsigned short* fcwb   = (unsigned short*)(ws + 2949120);     // 2097152 f
  unsigned short* pjwb   = (unsigned short*)(ws + 5046272);     // 2097152 f
  float*          bufB   = ws + 7143424;                        // 2097152 f (_s)
  unsigned short* smixb  = (unsigned short*)(ws + 9240576);     // 8388608 f (bf16 smix)
  float*          s1     = ws + 9240576;                        // overlay: smix dead after combine
  unsigned short* hmidb  = (unsigned short*)(ws + 9240576 + 2097152); // 4194304 f
  float*          outp   = (float*)d_out;

  // 0. weight conversions f32 -> bf16
  cvt_bf16_kernel<<<1024, 256, 0, stream>>>(inW,  wqb,   262144);   // Wq rows 0..1023
  cvt_bf16_kernel<<<1024, 256, 0, stream>>>(outW, outwb, 262144);
  cvt_bf16_kernel<<<4096, 256, 0, stream>>>(fcW,  fcwb,  1048576);
  cvt_bf16_kernel<<<4096, 256, 0, stream>>>(pjW,  pjwb,  1048576);
  cvt_bf16_kernel<<<128,  256, 0, stream>>>(syl1, syl1b, 32768);
  cvt_bf16_kernel<<<128,  256, 0, stream>>>(syl2, syl2b, 32768);

  // 1. te adaptor + te k/v
  adaptor_te_kernel<<<TT, 256, 0, stream>>>(te, telnW, telnB, tel1, tel2, f_te);
  te_kv_kernel<<<8, 256, 0, stream>>>(f_te, inW, inB, f_tek, f_tev);

  // 2. syno adaptor: h = LN(s) [bf16]
  ln_bf_kernel<<<NQ, 256, 0, stream>>>(s, sylnW, sylnB, bufAb);
  // 3. mid = h @ l1^T  [bf16 out]
  gemm_bf<0><<<dim3(1, 32), 256, 0, stream>>>(bufAb, syl1b, nullptr, nullptr, midb, NQ, 128, DD);
  // 4. _s = s + mid @ l2^T  [f32 out]
  gemm_bf<4><<<dim3(8, 32), 256, 0, stream>>>(midb, syl2b, nullptr, s, bufB, NQ, DD, 128);
  // 5. x = LN1(_s) [bf16]
  ln_bf_kernel<<<NQ, 256, 0, stream>>>(bufB, ln1_w, ln1_b, bufAb);
  // 6. s_q = (x @ Wq^T + bq) * 0.125 [bf16]
  gemm_bf<1><<<dim3(8, 32), 256, 0, stream>>>(bufAb, wqb, inB, nullptr, qbf, NQ, DD, DD);
  // 7. attention -> smix bf16
  attn_mfma<<<dim3(HH, TT, NN), 256, 0, stream>>>(attrs_k, attrs_v, qbf, f_tek, f_tev, pmask, smixb);
  // 8. conv+mean combine -> smm bf16
  combine_kernel<<<NQ, 256, 0, stream>>>(smixb, tconvW, tconvB, smmb);
  // 9. s1 = s + smm @ outW^T + outB [f32]
  gemm_bf<3><<<dim3(8, 32), 256, 0, stream>>>(smmb, outwb, outB, s, s1, NQ, DD, DD);
  // 10. x2 = LN2(s1) [bf16]
  ln_bf_kernel<<<NQ, 256, 0, stream>>>(s1, ln2_w, ln2_b, bufAb);
  // 11. hmid = qgelu(x2 @ fcW^T + fcB) [bf16]
  gemm_bf<2><<<dim3(32, 32), 256, 0, stream>>>(bufAb, fcwb, fcB, nullptr, hmidb, NQ, 4 * DD, DD);
  // 12. out = s1 + hmid @ pjW^T + pjB [f32]
  gemm_bf<3><<<dim3(8, 32), 256, 0, stream>>>(hmidb, pjwb, pjB, s1, outp, NQ, DD, 4 * DD);
}

// Round 5
// 275.900 us; speedup vs baseline: 7.3724x; 1.5489x over previous
//
#include <hip/hip_runtime.h>

#define NN 8
#define TT 8
#define LL 257
#define HH 16
#define CC 64
#define DD 1024
#define QQ 256
#define NQ (NN*QQ)   // 2048

typedef __attribute__((ext_vector_type(4))) float f32x4;
typedef __attribute__((ext_vector_type(4))) unsigned int u32x4;
typedef __attribute__((ext_vector_type(2))) unsigned int u32x2;

static __device__ __forceinline__ float4 ld4(const float* p) { return *(const float4*)p; }

static __device__ __forceinline__ void mfma16(f32x4& d, u32x4 a, u32x4 b) {
  asm("v_mfma_f32_16x16x32_bf16 %0, %1, %2, %0" : "+v"(d) : "v"(a), "v"(b));
}

static __device__ __forceinline__ unsigned int f2bf(float x) {
  unsigned int u = __float_as_uint(x);
  return (u + 0x7fffu + ((u >> 16) & 1u)) >> 16;
}
static __device__ __forceinline__ unsigned int pk2(float lo, float hi) {
  return f2bf(lo) | (f2bf(hi) << 16);
}
static __device__ __forceinline__ unsigned int cvtpk(float lo, float hi) {
  unsigned int r;
  asm("v_cvt_pk_bf16_f32 %0, %1, %2" : "=v"(r) : "v"(lo), "v"(hi));
  return r;
}
static __device__ __forceinline__ float bf2f(unsigned int u) {
  return __uint_as_float(u << 16);
}

typedef __attribute__((address_space(3))) unsigned char lds_t;
typedef const __attribute__((address_space(1))) unsigned char glb_t;
static __device__ __forceinline__ void gld16(const void* g, void* l) {
  __builtin_amdgcn_global_load_lds((glb_t*)g, (lds_t*)l, 16, 0, 0);
}

// ----------------------------------------------------- f32 -> bf16 ----
__global__ __launch_bounds__(256) void cvt_bf16_kernel(const float* __restrict__ in,
    unsigned short* __restrict__ out, int n4) {
  const int i = blockIdx.x * 256 + threadIdx.x;
  if (i < n4) {
    const float4 v = ld4(in + (size_t)i * 4);
    u32x2 p; p.x = pk2(v.x, v.y); p.y = pk2(v.z, v.w);
    *(u32x2*)(out + (size_t)i * 4) = p;
  }
}

// ------------------------------------------------- LN (bf16 output) ----
__global__ __launch_bounds__(256) void ln_bf_kernel(const float* __restrict__ in,
    const float* __restrict__ w, const float* __restrict__ b, unsigned short* __restrict__ out) {
  __shared__ float red[16];
  const int tid = threadIdx.x;
  const size_t row = blockIdx.x;
  const float4 v = ((const float4*)(in + row * DD))[tid];
  float s  = v.x + v.y + v.z + v.w;
  float ss = v.x*v.x + v.y*v.y + v.z*v.z + v.w*v.w;
  #pragma unroll
  for (int off = 32; off; off >>= 1) { s += __shfl_xor(s, off); ss += __shfl_xor(ss, off); }
  if ((tid & 63) == 0) { red[tid >> 6] = s; red[8 + (tid >> 6)] = ss; }
  __syncthreads();
  s  = red[0] + red[1] + red[2] + red[3];
  ss = red[8] + red[9] + red[10] + red[11];
  const float mean = s * (1.f / DD);
  const float var  = ss * (1.f / DD) - mean * mean;
  const float inv  = rsqrtf(var + 1e-5f);
  const float4 wv = ((const float4*)w)[tid];
  const float4 bv = ((const float4*)b)[tid];
  float o0 = (v.x - mean) * inv * wv.x + bv.x;
  float o1 = (v.y - mean) * inv * wv.y + bv.y;
  float o2 = (v.z - mean) * inv * wv.z + bv.z;
  float o3 = (v.w - mean) * inv * wv.w + bv.w;
  u32x2 p; p.x = pk2(o0, o1); p.y = pk2(o2, o3);
  *(u32x2*)(out + row * DD + tid * 4) = p;
}

// ----------------------------------------------------- te pipeline ----
// mid[t][j] = LN(te)[t] . l1[j]   (grid 32, wave per l1-row)
__global__ __launch_bounds__(256) void te_mid_kernel(
    const unsigned short* __restrict__ telnb, const float* __restrict__ l1,
    float* __restrict__ midf) {
  const int j = blockIdx.x * 4 + (threadIdx.x >> 6);
  const int l = threadIdx.x & 63;
  const float* lr = l1 + (size_t)j * DD + l * 16;
  float wv[16];
  #pragma unroll
  for (int q = 0; q < 4; ++q) {
    const float4 f = ld4(lr + q * 4);
    wv[q*4] = f.x; wv[q*4+1] = f.y; wv[q*4+2] = f.z; wv[q*4+3] = f.w;
  }
  float acc[8];
  #pragma unroll
  for (int t = 0; t < 8; ++t) {
    const unsigned short* hp = telnb + (size_t)t * DD + l * 16;
    const u32x4 h0 = *(const u32x4*)hp;
    const u32x4 h1 = *(const u32x4*)(hp + 8);
    float a = 0.f;
    #pragma unroll
    for (int e = 0; e < 4; ++e) {
      a += bf2f(h0[e] & 0xffffu) * wv[e*2]   + bf2f(h0[e] >> 16) * wv[e*2+1];
      a += bf2f(h1[e] & 0xffffu) * wv[8+e*2] + bf2f(h1[e] >> 16) * wv[8+e*2+1];
    }
    acc[t] = a;
  }
  #pragma unroll
  for (int off = 1; off < 64; off <<= 1)
    #pragma unroll
    for (int t = 0; t < 8; ++t) acc[t] += __shfl_xor(acc[t], off);
  if (l == 0) {
    #pragma unroll
    for (int t = 0; t < 8; ++t) midf[t * 128 + j] = acc[t];
  }
}

// _te[t][d] = te[t][d] + mid[t] . l2[d]   (grid 32)
__global__ __launch_bounds__(256) void te_fin_kernel(
    const float* __restrict__ midf, const float* __restrict__ l2,
    const float* __restrict__ te, float* __restrict__ tef) {
  __shared__ float mid_s[8 * 128];
  const int tid = threadIdx.x;
  ((f32x4*)mid_s)[tid] = ((const f32x4*)midf)[tid];
  __syncthreads();
  const int d = blockIdx.x * 32 + (tid >> 3);
  const int jseg = (tid & 7) * 16;
  const float* l2r = l2 + (size_t)d * 128 + jseg;
  float wv[16];
  #pragma unroll
  for (int q = 0; q < 4; ++q) {
    const float4 f = ld4(l2r + q * 4);
    wv[q*4] = f.x; wv[q*4+1] = f.y; wv[q*4+2] = f.z; wv[q*4+3] = f.w;
  }
  float acc[8];
  #pragma unroll
  for (int t = 0; t < 8; ++t) {
    float a = 0.f;
    #pragma unroll
    for (int i = 0; i < 16; ++i) a += mid_s[t * 128 + jseg + i] * wv[i];
    acc[t] = a;
  }
  #pragma unroll
  for (int off = 1; off < 8; off <<= 1)
    #pragma unroll
    for (int t = 0; t < 8; ++t) acc[t] += __shfl_xor(acc[t], off);
  if ((tid & 7) == 0) {
    #pragma unroll
    for (int t = 0; t < 8; ++t)
      tef[(size_t)t * DD + d] = te[(size_t)t * DD + d] + acc[t];
  }
}

// te_k/te_v = _te @ W[1024..3072]^T + b   (grid 64)
__global__ __launch_bounds__(256) void te_kv2_kernel(
    const float* __restrict__ tef, const float* __restrict__ W, const float* __restrict__ bias,
    float* __restrict__ tek, float* __restrict__ tev) {
  __shared__ float tes[8 * 1024];
  const int tid = threadIdx.x;
  #pragma unroll
  for (int i = 0; i < 8; ++i)
    ((f32x4*)tes)[tid + i * 256] = ((const f32x4*)tef)[tid + i * 256];
  __syncthreads();
  const int o = blockIdx.x * 32 + (tid >> 3);
  const int ks0 = (tid & 7) * 128;
  const float* wr = W + (size_t)(1024 + o) * DD + ks0;
  float acc[8] = {};
  for (int kk = 0; kk < 128; kk += 4) {
    const float4 w4 = ld4(wr + kk);
    #pragma unroll
    for (int t = 0; t < 8; ++t) {
      const float4 h4 = ld4(tes + t * 1024 + ks0 + kk);
      acc[t] += w4.x*h4.x + w4.y*h4.y + w4.z*h4.z + w4.w*h4.w;
    }
  }
  #pragma unroll
  for (int off = 1; off < 8; off <<= 1)
    #pragma unroll
    for (int t = 0; t < 8; ++t) acc[t] += __shfl_xor(acc[t], off);
  if ((tid & 7) == 0) {
    const float bv = bias[1024 + o];
    float* dst = (o < 1024) ? tek : tev;
    const int oc = o & 1023;
    #pragma unroll
    for (int t = 0; t < 8; ++t) dst[(size_t)t * DD + oc] = acc[t] + bv;
  }
}

// --------------------------------- bf16 MFMA GEMM, swizzled LDS -------
// C[M,N] = epi(A[M,K] @ W[N,K]^T); BM in {64,128}, BN=128, BK=64.
// LDS linear (global_load_lds) + inverse-swizzled global source; ds_read XOR.
// EPI: 0 ->bf16 | 1 (x+b)*0.125 ->bf16 | 2 qgelu(x+b) ->bf16 | 3 x+b+res ->f32 | 4 x+res ->f32
template<int EPI, int BM>
__global__ __launch_bounds__(256, 2) void gemm_bf(
    const unsigned short* __restrict__ A, const unsigned short* __restrict__ W,
    const float* __restrict__ bias, const float* __restrict__ res,
    void* __restrict__ Cv, int M, int N, int K) {
  constexpr int FR = BM / 32;            // A-frags per wave; also 32-row stage groups
  __shared__ unsigned short As[2][BM * 64];
  __shared__ unsigned short Bs[2][128 * 64];
  const int tid = threadIdx.x, w = tid >> 6, l = tid & 63;
  const int lc = l & 15, lg = l >> 4;
  const int m0 = blockIdx.y * BM, n0 = blockIdx.x * 128;
  const int wm = (w >> 1) * (BM / 2), wn = (w & 1) * 64;
  const int rrow = tid >> 3;             // 0..31
  const int sblk = (tid & 7) ^ (rrow & 7);   // pre-swizzled source block

  f32x4 acc[FR][4] = {};

  auto stagef = [&](int kt, int b) {
    const int k0 = kt * 64 + sblk * 8;
    #pragma unroll
    for (int r = 0; r < FR; ++r)         // FIX: stage ALL BM rows (FR x 32)
      gld16(A + (size_t)(m0 + r * 32 + rrow) * K + k0, &As[b][r * 2048 + w * 512]);
    #pragma unroll
    for (int r = 0; r < 4; ++r)
      gld16(W + (size_t)(n0 + r * 32 + rrow) * K + k0, &Bs[b][r * 2048 + w * 512]);
  };
  auto computef = [&](int b) {
    const int bx = lc & 7;
    #pragma unroll
    for (int ks = 0; ks < 2; ++ks) {
      u32x4 af[FR], bfr[4];
      #pragma unroll
      for (int i = 0; i < FR; ++i)
        af[i] = *(const u32x4*)&As[b][(wm + i * 16 + lc) * 64 + (((ks * 4 + lg) ^ bx)) * 8];
      #pragma unroll
      for (int j = 0; j < 4; ++j)
        bfr[j] = *(const u32x4*)&Bs[b][(wn + j * 16 + lc) * 64 + (((ks * 4 + lg) ^ bx)) * 8];
      #pragma unroll
      for (int i = 0; i < FR; ++i)
        #pragma unroll
        for (int j = 0; j < 4; ++j)
          mfma16(acc[i][j], af[i], bfr[j]);
    }
  };

  const int NT = K >> 6;
  stagef(0, 0);
  asm volatile("s_waitcnt vmcnt(0)" ::: "memory");
  __builtin_amdgcn_s_barrier();
  int cur = 0;
  for (int kt = 0; kt < NT - 1; ++kt) {
    stagef(kt + 1, cur ^ 1);
    computef(cur);
    asm volatile("s_waitcnt vmcnt(0)" ::: "memory");
    __builtin_amdgcn_s_barrier();
    cur ^= 1;
  }
  computef(cur);

  float bias4[4];
  if (EPI == 1 || EPI == 2 || EPI == 3) {
    #pragma unroll
    for (int j = 0; j < 4; ++j) bias4[j] = bias[n0 + wn + j * 16 + lc];
  }
  #pragma unroll
  for (int i = 0; i < FR; ++i) {
    #pragma unroll
    for (int j = 0; j < 4; ++j) {
      const int col = n0 + wn + j * 16 + lc;
      #pragma unroll
      for (int r = 0; r < 4; ++r) {
        const int row = m0 + wm + i * 16 + lg * 4 + r;
        float x = acc[i][j][r];
        if (EPI == 0) {
          ((unsigned short*)Cv)[(size_t)row * N + col] = (unsigned short)f2bf(x);
        } else if (EPI == 1) {
          x = (x + bias4[j]) * 0.125f;
          ((unsigned short*)Cv)[(size_t)row * N + col] = (unsigned short)f2bf(x);
        } else if (EPI == 2) {
          x += bias4[j];
          x = x / (1.f + __expf(-1.702f * x));
          ((unsigned short*)Cv)[(size_t)row * N + col] = (unsigned short)f2bf(x);
        } else if (EPI == 3) {
          x += bias4[j] + res[(size_t)row * N + col];
          ((float*)Cv)[(size_t)row * N + col] = x;
        } else {
          x += res[(size_t)row * N + col];
          ((float*)Cv)[(size_t)row * N + col] = x;
        }
      }
    }
  }
}

// -------------------------------------------------- MFMA attention ----
// te_k folded as per-q scalar bias (qte = q.te_k); te_v folded in epilogue
// (softmax rows sum to 1). K/V staged raw with v_cvt_pk_bf16_f32.
__global__ __launch_bounds__(256, 2) void attn_mfma(
    const float* __restrict__ ak, const float* __restrict__ av,
    const unsigned short* __restrict__ qbf,
    const float* __restrict__ tek, const float* __restrict__ tev,
    const float* __restrict__ mask, unsigned short* __restrict__ smix) {
  const int h = blockIdx.x, t = blockIdx.y, n = blockIdx.z;
  const int tid = threadIdx.x, w = tid >> 6, l = tid & 63;
  const int lc = l & 15, lg = l >> 4;
  __shared__ unsigned short Ks[64][72];
  __shared__ unsigned short Vt[64][72];
  __shared__ unsigned short Pl[4][64][72];

  u32x4 qf[4][2];
  {
    const unsigned short* qb = qbf + ((size_t)(n * QQ + w * 64 + lc)) * DD + h * CC + lg * 8;
    #pragma unroll
    for (int fnq = 0; fnq < 4; ++fnq)
      #pragma unroll
      for (int ks = 0; ks < 2; ++ks)
        qf[fnq][ks] = *(const u32x4*)(qb + (size_t)fnq * 16 * DD + ks * 32);
  }
  // qte[fnq] = (q*scale) . te_k  for q = w*64+fnq*16+lc
  float qte4[4];
  {
    float tkc[16];
    const float* tp = tek + (size_t)t * DD + h * CC + lg * 8;
    #pragma unroll
    for (int ks = 0; ks < 2; ++ks) {
      const float4 a = ld4(tp + ks * 32);
      const float4 b = ld4(tp + ks * 32 + 4);
      tkc[ks*8]   = a.x; tkc[ks*8+1] = a.y; tkc[ks*8+2] = a.z; tkc[ks*8+3] = a.w;
      tkc[ks*8+4] = b.x; tkc[ks*8+5] = b.y; tkc[ks*8+6] = b.z; tkc[ks*8+7] = b.w;
    }
    #pragma unroll
    for (int fnq = 0; fnq < 4; ++fnq) {
      float p = 0.f;
      #pragma unroll
      for (int ks = 0; ks < 2; ++ks)
        #pragma unroll
        for (int e = 0; e < 4; ++e) {
          const unsigned int u = qf[fnq][ks][e];
          p += bf2f(u & 0xffffu) * tkc[ks*8 + e*2];
          p += bf2f(u >> 16)     * tkc[ks*8 + e*2 + 1];
        }
      p += __shfl_xor(p, 16);
      p += __shfl_xor(p, 32);
      qte4[fnq] = p;
    }
  }

  f32x4 oacc[4][4] = {};
  float mrun[4], lrun[4];
  #pragma unroll
  for (int i = 0; i < 4; ++i) { mrun[i] = -1e30f; lrun[i] = 0.f; }

  const size_t krow0 = (((size_t)(n * TT + t) * LL + 1) * HH + h) * CC;
  const float* mbase = mask + (size_t)(w * 64) * QQ;

  for (int c0 = 0; c0 < QQ; c0 += 64) {
    __syncthreads();
    {   // stage K row-major [key][c]
      const int kr = tid >> 2, cs = (tid & 3) * 16;
      const float* kp = ak + krow0 + (size_t)(c0 + kr) * (HH * CC) + cs;
      const float4 k0 = ld4(kp), k1 = ld4(kp + 4), k2 = ld4(kp + 8), k3 = ld4(kp + 12);
      u32x4 pa; pa.x = cvtpk(k0.x, k0.y); pa.y = cvtpk(k0.z, k0.w);
      pa.z = cvtpk(k1.x, k1.y); pa.w = cvtpk(k1.z, k1.w);
      u32x4 pb; pb.x = cvtpk(k2.x, k2.y); pb.y = cvtpk(k2.z, k2.w);
      pb.z = cvtpk(k3.x, k3.y); pb.w = cvtpk(k3.z, k3.w);
      *(u32x4*)&Ks[kr][cs] = pa;
      *(u32x4*)&Ks[kr][cs + 8] = pb;
    }
    {   // stage V transposed [c][key]
      const int kp2 = tid & 31, ch = tid >> 5;
      const float* vr0 = av + krow0 + (size_t)(c0 + 2 * kp2) * (HH * CC) + ch * 8;
      const float* vr1 = vr0 + HH * CC;
      const float4 a0 = ld4(vr0), a1 = ld4(vr0 + 4);
      const float4 b0 = ld4(vr1), b1 = ld4(vr1 + 4);
      const float va[8] = {a0.x,a0.y,a0.z,a0.w,a1.x,a1.y,a1.z,a1.w};
      const float vb[8] = {b0.x,b0.y,b0.z,b0.w,b1.x,b1.y,b1.z,b1.w};
      #pragma unroll
      for (int i = 0; i < 8; ++i)
        *(unsigned int*)&Vt[ch * 8 + i][2 * kp2] = cvtpk(va[i], vb[i]);
    }
    __syncthreads();

    f32x4 sf[4][4] = {};
    #pragma unroll
    for (int ks = 0; ks < 2; ++ks) {
      u32x4 kf[4];
      #pragma unroll
      for (int fmk = 0; fmk < 4; ++fmk)
        kf[fmk] = *(const u32x4*)&Ks[fmk * 16 + lc][ks * 32 + lg * 8];
      #pragma unroll
      for (int fmk = 0; fmk < 4; ++fmk)
        #pragma unroll
        for (int fnq = 0; fnq < 4; ++fnq)
          mfma16(sf[fmk][fnq], kf[fmk], qf[fnq][ks]);
    }

    #pragma unroll
    for (int fnq = 0; fnq < 4; ++fnq) {
      const float* mrow = mbase + (size_t)(fnq * 16 + lc) * QQ + c0 + lg * 4;
      const float qv = qte4[fnq];
      #pragma unroll
      for (int fmk = 0; fmk < 4; ++fmk) {
        const f32x4 mk = *(const f32x4*)(mrow + fmk * 16);
        sf[fmk][fnq] += mk + qv;
      }
      float mx = -1e30f;
      #pragma unroll
      for (int fmk = 0; fmk < 4; ++fmk) {
        mx = fmaxf(mx, fmaxf(fmaxf(sf[fmk][fnq][0], sf[fmk][fnq][1]),
                             fmaxf(sf[fmk][fnq][2], sf[fmk][fnq][3])));
      }
      mx = fmaxf(mx, __shfl_xor(mx, 16));
      mx = fmaxf(mx, __shfl_xor(mx, 32));
      const float mnew = fmaxf(mrun[fnq], mx);
      const float corr = __expf(mrun[fnq] - mnew);
      mrun[fnq] = mnew;
      float ls = 0.f;
      #pragma unroll
      for (int fmk = 0; fmk < 4; ++fmk) {
        const float p0 = __expf(sf[fmk][fnq][0] - mnew);
        const float p1 = __expf(sf[fmk][fnq][1] - mnew);
        const float p2 = __expf(sf[fmk][fnq][2] - mnew);
        const float p3 = __expf(sf[fmk][fnq][3] - mnew);
        ls += (p0 + p1) + (p2 + p3);
        u32x2 pw; pw.x = cvtpk(p0, p1); pw.y = cvtpk(p2, p3);
        *(u32x2*)&Pl[w][fnq * 16 + lc][fmk * 16 + lg * 4] = pw;
      }
      ls += __shfl_xor(ls, 16);
      ls += __shfl_xor(ls, 32);
      lrun[fnq] = lrun[fnq] * corr + ls;
      #pragma unroll
      for (int fmc = 0; fmc < 4; ++fmc) oacc[fmc][fnq] *= corr;
    }

    #pragma unroll
    for (int ks = 0; ks < 2; ++ks) {
      u32x4 vf[4], pf[4];
      #pragma unroll
      for (int fmc = 0; fmc < 4; ++fmc)
        vf[fmc] = *(const u32x4*)&Vt[fmc * 16 + lc][ks * 32 + lg * 8];
      #pragma unroll
      for (int fnq = 0; fnq < 4; ++fnq)
        pf[fnq] = *(const u32x4*)&Pl[w][fnq * 16 + lc][ks * 32 + lg * 8];
      #pragma unroll
      for (int fmc = 0; fmc < 4; ++fmc)
        #pragma unroll
        for (int fnq = 0; fnq < 4; ++fnq)
          mfma16(oacc[fmc][fnq], vf[fmc], pf[fnq]);
    }
  }

  // epilogue: O/l + te_v  -> smix bf16
  f32x4 tev4[4];
  {
    const float* tvp = tev + (size_t)t * DD + h * CC + lg * 4;
    #pragma unroll
    for (int fmc = 0; fmc < 4; ++fmc) tev4[fmc] = *(const f32x4*)(tvp + fmc * 16);
  }
  #pragma unroll
  for (int fnq = 0; fnq < 4; ++fnq) {
    const float inv = 1.f / lrun[fnq];
    const int qg = w * 64 + fnq * 16 + lc;
    unsigned short* op = smix + ((((size_t)(n * TT + t) * QQ + qg) * HH + h) * CC + lg * 4);
    #pragma unroll
    for (int fmc = 0; fmc < 4; ++fmc) {
      const f32x4 o = oacc[fmc][fnq] * inv + tev4[fmc];
      u32x2 p; p.x = cvtpk(o[0], o[1]); p.y = cvtpk(o[2], o[3]);
      *(u32x2*)(op + fmc * 16) = p;
    }
  }
}

// -------------------------------------------- conv3+mean_t combine ----
__global__ __launch_bounds__(256) void combine_kernel(
    const unsigned short* __restrict__ smix, const float* __restrict__ cw,
    const float* __restrict__ cb, unsigned short* __restrict__ smm) {
  const int nq = blockIdx.x;
  const int d = threadIdx.x * 4;
  const int n = nq >> 8, q = nq & 255;
  const unsigned short* base = smix + ((size_t)n * TT * QQ + q) * DD + d;
  float S[4] = {0.f, 0.f, 0.f, 0.f};
  float X0[4], X7[4];
  #pragma unroll
  for (int t = 0; t < TT; ++t) {
    const u32x2 pv = *(const u32x2*)(base + (size_t)t * QQ * DD);
    const float v[4] = {bf2f(pv.x & 0xffffu), bf2f(pv.x >> 16),
                        bf2f(pv.y & 0xffffu), bf2f(pv.y >> 16)};
    if (t == 0) { X0[0]=v[0]; X0[1]=v[1]; X0[2]=v[2]; X0[3]=v[3]; }
    if (t == 7) { X7[0]=v[0]; X7[1]=v[1]; X7[2]=v[2]; X7[3]=v[3]; }
    #pragma unroll
    for (int i = 0; i < 4; ++i) S[i] += v[i];
  }
  float o[4];
  #pragma unroll
  for (int i = 0; i < 4; ++i) {
    const int chn = d + i;
    const float w0 = cw[chn*3+0], w1 = cw[chn*3+1], w2 = cw[chn*3+2];
    o[i] = ((1.f + w0 + w1 + w2) * S[i] - w0 * X7[i] - w2 * X0[i]) * 0.125f + cb[chn];
  }
  u32x2 p; p.x = pk2(o[0], o[1]); p.y = pk2(o[2], o[3]);
  *(u32x2*)(smm + (size_t)nq * DD + d) = p;
}

// ------------------------------------------------------------ launch ----
extern "C" void kernel_launch(void* const* d_in, const int* in_sizes, int n_in,
                              void* d_out, int out_size, void* d_ws, size_t ws_size,
                              hipStream_t stream) {
  const float* attrs_k = (const float*)d_in[0];
  const float* attrs_v = (const float*)d_in[1];
  const float* s       = (const float*)d_in[2];
  const float* te      = (const float*)d_in[3];
  const float* pmask   = (const float*)d_in[4];
  const float* ln1_w   = (const float*)d_in[5];
  const float* ln1_b   = (const float*)d_in[6];
  const float* inW     = (const float*)d_in[7];
  const float* inB     = (const float*)d_in[8];
  const float* outW    = (const float*)d_in[9];
  const float* outB    = (const float*)d_in[10];
  const float* ln2_w   = (const float*)d_in[11];
  const float* ln2_b   = (const float*)d_in[12];
  const float* fcW     = (const float*)d_in[13];
  const float* fcB     = (const float*)d_in[14];
  const float* pjW     = (const float*)d_in[15];
  const float* pjB     = (const float*)d_in[16];
  const float* sylnW   = (const float*)d_in[17];
  const float* sylnB   = (const float*)d_in[18];
  const float* syl1    = (const float*)d_in[19];
  const float* syl2    = (const float*)d_in[20];
  const float* telnW   = (const float*)d_in[21];
  const float* telnB   = (const float*)d_in[22];
  const float* tel1    = (const float*)d_in[23];
  const float* tel2    = (const float*)d_in[24];
  const float* tconvW  = (const float*)d_in[25];
  const float* tconvB  = (const float*)d_in[26];

  float* ws = (float*)d_ws;
  float*          f_te   = ws;                                  // 8192 (= _te)
  float*          f_tek  = ws + 8192;                           // 8192
  float*          f_tev  = ws + 16384;                          // 8192
  unsigned short* telnb  = (unsigned short*)(ws + 24576);       // 4096 f
  float*          midf   = ws + 28672;                          // 1024 f
  unsigned short* syl1b  = (unsigned short*)(ws + 32768);       // 65536 f
  unsigned short* syl2b  = (unsigned short*)(ws + 98304);       // 65536 f
  unsigned short* midb   = (unsigned short*)(ws + 163840);      // 131072 f
  unsigned short* bufAb  = (unsigned short*)(ws + 327680);      // 524288 f (LN outs)
  unsigned short* qbf    = (unsigned short*)(ws + 851968);      // 524288 f
  unsigned short* smmb   = (unsigned short*)(ws + 1376256);     // 524288 f
  unsigned short* wqb    = (unsigned short*)(ws + 1900544);     // 524288 f
  unsigned short* outwb  = (unsigned short*)(ws + 2424832);     // 524288 f
  unsigned short* fcwb   = (unsigned short*)(ws + 2949120);     // 2097152 f
  unsigned short* pjwb   = (unsigned short*)(ws + 5046272);     // 2097152 f
  float*          bufB   = ws + 7143424;                        // 2097152 f (_s)
  unsigned short* smixb  = (unsigned short*)(ws + 9240576);     // 8388608 f region
  float*          s1     = ws + 9240576;                        // overlay (smix dead)
  unsigned short* hmidb  = (unsigned short*)(ws + 9240576 + 2097152); // 4194304 f
  float*          outp   = (float*)d_out;

  // 0. weight conversions f32 -> bf16
  cvt_bf16_kernel<<<1024, 256, 0, stream>>>(inW,  wqb,   262144);
  cvt_bf16_kernel<<<1024, 256, 0, stream>>>(outW, outwb, 262144);
  cvt_bf16_kernel<<<4096, 256, 0, stream>>>(fcW,  fcwb,  1048576);
  cvt_bf16_kernel<<<4096, 256, 0, stream>>>(pjW,  pjwb,  1048576);
  cvt_bf16_kernel<<<128,  256, 0, stream>>>(syl1, syl1b, 32768);
  cvt_bf16_kernel<<<128,  256, 0, stream>>>(syl2, syl2b, 32768);

  // 1. te adaptor pipeline + te k/v
  ln_bf_kernel<<<TT, 256, 0, stream>>>(te, telnW, telnB, telnb);
  te_mid_kernel<<<32, 256, 0, stream>>>(telnb, tel1, midf);
  te_fin_kernel<<<32, 256, 0, stream>>>(midf, tel2, te, f_te);
  te_kv2_kernel<<<64, 256, 0, stream>>>(f_te, inW, inB, f_tek, f_tev);

  // 2. syno adaptor: h = LN(s) [bf16]
  ln_bf_kernel<<<NQ, 256, 0, stream>>>(s, sylnW, sylnB, bufAb);
  // 3. mid = h @ l1^T  [bf16]
  gemm_bf<0, 64><<<dim3(1, 32), 256, 0, stream>>>(bufAb, syl1b, nullptr, nullptr, midb, NQ, 128, DD);
  // 4. _s = s + mid @ l2^T  [f32]
  gemm_bf<4, 64><<<dim3(8, 32), 256, 0, stream>>>(midb, syl2b, nullptr, s, bufB, NQ, DD, 128);
  // 5. x = LN1(_s) [bf16]
  ln_bf_kernel<<<NQ, 256, 0, stream>>>(bufB, ln1_w, ln1_b, bufAb);
  // 6. s_q = (x @ Wq^T + bq) * 0.125 [bf16]
  gemm_bf<1, 64><<<dim3(8, 32), 256, 0, stream>>>(bufAb, wqb, inB, nullptr, qbf, NQ, DD, DD);
  // 7. attention -> smix bf16 (includes te_v)
  attn_mfma<<<dim3(HH, TT, NN), 256, 0, stream>>>(attrs_k, attrs_v, qbf, f_tek, f_tev, pmask, smixb);
  // 8. conv+mean combine -> smm bf16
  combine_kernel<<<NQ, 256, 0, stream>>>(smixb, tconvW, tconvB, smmb);
  // 9. s1 = s + smm @ outW^T + outB [f32]
  gemm_bf<3, 64><<<dim3(8, 32), 256, 0, stream>>>(smmb, outwb, outB, s, s1, NQ, DD, DD);
  // 10. x2 = LN2(s1) [bf16]
  ln_bf_kernel<<<NQ, 256, 0, stream>>>(s1, ln2_w, ln2_b, bufAb);
  // 11. hmid = qgelu(x2 @ fcW^T + fcB) [bf16] (128x128 tile)
  gemm_bf<2, 128><<<dim3(32, 16), 256, 0, stream>>>(bufAb, fcwb, fcB, nullptr, hmidb, NQ, 4 * DD, DD);
  // 12. out = s1 + hmid @ pjW^T + pjB [f32]
  gemm_bf<3, 64><<<dim3(8, 32), 256, 0, stream>>>(hmidb, pjwb, pjB, s1, outp, NQ, DD, 4 * DD);
}

// Round 8
// 260.007 us; speedup vs baseline: 7.8230x; 1.0611x over previous
//
#include <hip/hip_runtime.h>

#define NN 8
#define TT 8
#define LL 257
#define HH 16
#define CC 64
#define DD 1024
#define QQ 256
#define NQ (NN*QQ)   // 2048

typedef __attribute__((ext_vector_type(4))) float f32x4;
typedef __attribute__((ext_vector_type(4))) unsigned int u32x4;
typedef __attribute__((ext_vector_type(2))) unsigned int u32x2;

static __device__ __forceinline__ float4 ld4(const float* p) { return *(const float4*)p; }

static __device__ __forceinline__ void mfma16(f32x4& d, u32x4 a, u32x4 b) {
  asm("v_mfma_f32_16x16x32_bf16 %0, %1, %2, %0" : "+v"(d) : "v"(a), "v"(b));
}

static __device__ __forceinline__ unsigned int f2bf(float x) {
  unsigned int u = __float_as_uint(x);
  return (u + 0x7fffu + ((u >> 16) & 1u)) >> 16;
}
static __device__ __forceinline__ unsigned int pk2(float lo, float hi) {
  return f2bf(lo) | (f2bf(hi) << 16);
}
static __device__ __forceinline__ unsigned int cvtpk(float lo, float hi) {
  unsigned int r;
  asm("v_cvt_pk_bf16_f32 %0, %1, %2" : "=v"(r) : "v"(lo), "v"(hi));
  return r;
}
static __device__ __forceinline__ float bf2f(unsigned int u) {
  return __uint_as_float(u << 16);
}

typedef __attribute__((address_space(3))) unsigned char lds_t;
typedef const __attribute__((address_space(1))) unsigned char glb_t;
static __device__ __forceinline__ void gld16(const void* g, void* l) {
  __builtin_amdgcn_global_load_lds((glb_t*)g, (lds_t*)l, 16, 0, 0);
}

// ------------------------------------------- fused f32 -> bf16 cvt ----
__global__ __launch_bounds__(256) void cvt_all_kernel(
    const float* __restrict__ inW, const float* __restrict__ outW,
    const float* __restrict__ fcW, const float* __restrict__ pjW,
    const float* __restrict__ syl1, const float* __restrict__ syl2,
    unsigned short* __restrict__ wqb, unsigned short* __restrict__ outwb,
    unsigned short* __restrict__ fcwb, unsigned short* __restrict__ pjwb,
    unsigned short* __restrict__ syl1b, unsigned short* __restrict__ syl2b) {
  const int i = blockIdx.x * 256 + threadIdx.x;
  const float* src; unsigned short* dst; int off;
  if (i < 262144)       { src = inW;  dst = wqb;   off = i; }
  else if (i < 524288)  { src = outW; dst = outwb; off = i - 262144; }
  else if (i < 1572864) { src = fcW;  dst = fcwb;  off = i - 524288; }
  else if (i < 2621440) { src = pjW;  dst = pjwb;  off = i - 1572864; }
  else if (i < 2654208) { src = syl1; dst = syl1b; off = i - 2621440; }
  else                  { src = syl2; dst = syl2b; off = i - 2654208; }
  const float4 v = ld4(src + (size_t)off * 4);
  u32x2 p; p.x = pk2(v.x, v.y); p.y = pk2(v.z, v.w);
  *(u32x2*)(dst + (size_t)off * 4) = p;
}

// ------------------------------------------------- LN (bf16 output) ----
__global__ __launch_bounds__(256) void ln_bf_kernel(const float* __restrict__ in,
    const float* __restrict__ w, const float* __restrict__ b, unsigned short* __restrict__ out) {
  __shared__ float red[16];
  const int tid = threadIdx.x;
  const size_t row = blockIdx.x;
  const float4 v = ((const float4*)(in + row * DD))[tid];
  float s  = v.x + v.y + v.z + v.w;
  float ss = v.x*v.x + v.y*v.y + v.z*v.z + v.w*v.w;
  #pragma unroll
  for (int off = 32; off; off >>= 1) { s += __shfl_xor(s, off); ss += __shfl_xor(ss, off); }
  if ((tid & 63) == 0) { red[tid >> 6] = s; red[8 + (tid >> 6)] = ss; }
  __syncthreads();
  s  = red[0] + red[1] + red[2] + red[3];
  ss = red[8] + red[9] + red[10] + red[11];
  const float mean = s * (1.f / DD);
  const float var  = ss * (1.f / DD) - mean * mean;
  const float inv  = rsqrtf(var + 1e-5f);
  const float4 wv = ((const float4*)w)[tid];
  const float4 bv = ((const float4*)b)[tid];
  float o0 = (v.x - mean) * inv * wv.x + bv.x;
  float o1 = (v.y - mean) * inv * wv.y + bv.y;
  float o2 = (v.z - mean) * inv * wv.z + bv.z;
  float o3 = (v.w - mean) * inv * wv.w + bv.w;
  u32x2 p; p.x = pk2(o0, o1); p.y = pk2(o2, o3);
  *(u32x2*)(out + row * DD + tid * 4) = p;
}

// ----------------------------------------------------- te pipeline ----
__global__ __launch_bounds__(256) void te_mid_kernel(
    const unsigned short* __restrict__ telnb, const float* __restrict__ l1,
    float* __restrict__ midf) {
  const int j = blockIdx.x * 4 + (threadIdx.x >> 6);
  const int l = threadIdx.x & 63;
  const float* lr = l1 + (size_t)j * DD + l * 16;
  float wv[16];
  #pragma unroll
  for (int q = 0; q < 4; ++q) {
    const float4 f = ld4(lr + q * 4);
    wv[q*4] = f.x; wv[q*4+1] = f.y; wv[q*4+2] = f.z; wv[q*4+3] = f.w;
  }
  float acc[8];
  #pragma unroll
  for (int t = 0; t < 8; ++t) {
    const unsigned short* hp = telnb + (size_t)t * DD + l * 16;
    const u32x4 h0 = *(const u32x4*)hp;
    const u32x4 h1 = *(const u32x4*)(hp + 8);
    float a = 0.f;
    #pragma unroll
    for (int e = 0; e < 4; ++e) {
      a += bf2f(h0[e] & 0xffffu) * wv[e*2]   + bf2f(h0[e] >> 16) * wv[e*2+1];
      a += bf2f(h1[e] & 0xffffu) * wv[8+e*2] + bf2f(h1[e] >> 16) * wv[8+e*2+1];
    }
    acc[t] = a;
  }
  #pragma unroll
  for (int off = 1; off < 64; off <<= 1)
    #pragma unroll
    for (int t = 0; t < 8; ++t) acc[t] += __shfl_xor(acc[t], off);
  if (l == 0) {
    #pragma unroll
    for (int t = 0; t < 8; ++t) midf[t * 128 + j] = acc[t];
  }
}

__global__ __launch_bounds__(256) void te_fin_kernel(
    const float* __restrict__ midf, const float* __restrict__ l2,
    const float* __restrict__ te, float* __restrict__ tef) {
  __shared__ float mid_s[8 * 128];
  const int tid = threadIdx.x;
  ((f32x4*)mid_s)[tid] = ((const f32x4*)midf)[tid];
  __syncthreads();
  const int d = blockIdx.x * 32 + (tid >> 3);
  const int jseg = (tid & 7) * 16;
  const float* l2r = l2 + (size_t)d * 128 + jseg;
  float wv[16];
  #pragma unroll
  for (int q = 0; q < 4; ++q) {
    const float4 f = ld4(l2r + q * 4);
    wv[q*4] = f.x; wv[q*4+1] = f.y; wv[q*4+2] = f.z; wv[q*4+3] = f.w;
  }
  float acc[8];
  #pragma unroll
  for (int t = 0; t < 8; ++t) {
    float a = 0.f;
    #pragma unroll
    for (int i = 0; i < 16; ++i) a += mid_s[t * 128 + jseg + i] * wv[i];
    acc[t] = a;
  }
  #pragma unroll
  for (int off = 1; off < 8; off <<= 1)
    #pragma unroll
    for (int t = 0; t < 8; ++t) acc[t] += __shfl_xor(acc[t], off);
  if ((tid & 7) == 0) {
    #pragma unroll
    for (int t = 0; t < 8; ++t)
      tef[(size_t)t * DD + d] = te[(size_t)t * DD + d] + acc[t];
  }
}

__global__ __launch_bounds__(256) void te_kv2_kernel(
    const float* __restrict__ tef, const float* __restrict__ W, const float* __restrict__ bias,
    float* __restrict__ tek, float* __restrict__ tev) {
  __shared__ float tes[8 * 1024];
  const int tid = threadIdx.x;
  #pragma unroll
  for (int i = 0; i < 8; ++i)
    ((f32x4*)tes)[tid + i * 256] = ((const f32x4*)tef)[tid + i * 256];
  __syncthreads();
  const int o = blockIdx.x * 32 + (tid >> 3);
  const int ks0 = (tid & 7) * 128;
  const float* wr = W + (size_t)(1024 + o) * DD + ks0;
  float acc[8] = {};
  for (int kk = 0; kk < 128; kk += 4) {
    const float4 w4 = ld4(wr + kk);
    #pragma unroll
    for (int t = 0; t < 8; ++t) {
      const float4 h4 = ld4(tes + t * 1024 + ks0 + kk);
      acc[t] += w4.x*h4.x + w4.y*h4.y + w4.z*h4.z + w4.w*h4.w;
    }
  }
  #pragma unroll
  for (int off = 1; off < 8; off <<= 1)
    #pragma unroll
    for (int t = 0; t < 8; ++t) acc[t] += __shfl_xor(acc[t], off);
  if ((tid & 7) == 0) {
    const float bv = bias[1024 + o];
    float* dst = (o < 1024) ? tek : tev;
    const int oc = o & 1023;
    #pragma unroll
    for (int t = 0; t < 8; ++t) dst[(size_t)t * DD + oc] = acc[t] + bv;
  }
}

// --------------------------------- bf16 MFMA GEMM (proven 2-phase) ----
// C[M,N] = epi(A[M,K] @ W[N,K]^T); BM in {64,128}, BN=128, BK=64.
// Round-5-proven loop: stage(kt+1) -> compute(kt) -> vmcnt(0):::memory ->
// s_barrier (motion-safe: every barrier is adjacent to a full-drain
// memory-clobbered asm). 1D grid + XCD chunk swizzle kept (index math only).
template<int EPI, int BM>
__global__ __launch_bounds__(256, 2) void gemm_bf(
    const unsigned short* __restrict__ A, const unsigned short* __restrict__ W,
    const float* __restrict__ bias, const float* __restrict__ res,
    void* __restrict__ Cv, int M, int N, int K, int ny) {
  constexpr int FR = BM / 32;            // A-frags per wave; stage groups of 32 rows
  __shared__ unsigned short As[2][BM * 64];
  __shared__ unsigned short Bs[2][128 * 64];
  const int tid = threadIdx.x, w = tid >> 6, l = tid & 63;
  const int lc = l & 15, lg = l >> 4;
  const int nb = gridDim.x;
  const int cid = (blockIdx.x & 7) * (nb >> 3) + (blockIdx.x >> 3);  // XCD chunk
  const int bxt = cid / ny, byt = cid - bxt * ny;
  const int m0 = byt * BM, n0 = bxt * 128;
  const int wm = (w >> 1) * (BM / 2), wn = (w & 1) * 64;
  const int rrow = tid >> 3;             // 0..31
  const int sblk = (tid & 7) ^ (rrow & 7);   // pre-swizzled source block

  f32x4 acc[FR][4] = {};

  auto stagef = [&](int kt, int b) {
    const int k0 = kt * 64 + sblk * 8;
    #pragma unroll
    for (int r = 0; r < FR; ++r)
      gld16(A + (size_t)(m0 + r * 32 + rrow) * K + k0, &As[b][r * 2048 + w * 512]);
    #pragma unroll
    for (int r = 0; r < 4; ++r)
      gld16(W + (size_t)(n0 + r * 32 + rrow) * K + k0, &Bs[b][r * 2048 + w * 512]);
  };
  auto computef = [&](int b) {
    const int kx = lc & 7;
    #pragma unroll
    for (int ks = 0; ks < 2; ++ks) {
      u32x4 af[FR], bfr[4];
      #pragma unroll
      for (int i = 0; i < FR; ++i)
        af[i] = *(const u32x4*)&As[b][(wm + i * 16 + lc) * 64 + ((ks * 4 + lg) ^ kx) * 8];
      #pragma unroll
      for (int j = 0; j < 4; ++j)
        bfr[j] = *(const u32x4*)&Bs[b][(wn + j * 16 + lc) * 64 + ((ks * 4 + lg) ^ kx) * 8];
      #pragma unroll
      for (int i = 0; i < FR; ++i)
        #pragma unroll
        for (int j = 0; j < 4; ++j)
          mfma16(acc[i][j], af[i], bfr[j]);
    }
  };

  const int NT = K >> 6;
  stagef(0, 0);
  asm volatile("s_waitcnt vmcnt(0)" ::: "memory");
  __builtin_amdgcn_s_barrier();
  int cur = 0;
  for (int kt = 0; kt < NT - 1; ++kt) {
    stagef(kt + 1, cur ^ 1);
    computef(cur);
    asm volatile("s_waitcnt vmcnt(0)" ::: "memory");
    __builtin_amdgcn_s_barrier();
    cur ^= 1;
  }
  computef(cur);

  float bias4[4];
  if (EPI == 1 || EPI == 2 || EPI == 3) {
    #pragma unroll
    for (int j = 0; j < 4; ++j) bias4[j] = bias[n0 + wn + j * 16 + lc];
  }
  #pragma unroll
  for (int i = 0; i < FR; ++i) {
    #pragma unroll
    for (int j = 0; j < 4; ++j) {
      const int col = n0 + wn + j * 16 + lc;
      #pragma unroll
      for (int r = 0; r < 4; ++r) {
        const int row = m0 + wm + i * 16 + lg * 4 + r;
        float x = acc[i][j][r];
        if (EPI == 0) {
          ((unsigned short*)Cv)[(size_t)row * N + col] = (unsigned short)f2bf(x);
        } else if (EPI == 1) {
          x = (x + bias4[j]) * 0.125f;
          ((unsigned short*)Cv)[(size_t)row * N + col] = (unsigned short)f2bf(x);
        } else if (EPI == 2) {
          x += bias4[j];
          x = x / (1.f + __expf(-1.702f * x));
          ((unsigned short*)Cv)[(size_t)row * N + col] = (unsigned short)f2bf(x);
        } else if (EPI == 3) {
          x += bias4[j] + res[(size_t)row * N + col];
          ((float*)Cv)[(size_t)row * N + col] = x;
        } else {
          x += res[(size_t)row * N + col];
          ((float*)Cv)[(size_t)row * N + col] = x;
        }
      }
    }
  }
}

// -------------------------------------------------- MFMA attention ----
// Round-5-proven staging (direct global -> cvtpk -> LDS); setprio kept
// around MFMA clusters (scheduling hint only).
__global__ __launch_bounds__(256, 2) void attn_mfma(
    const float* __restrict__ ak, const float* __restrict__ av,
    const unsigned short* __restrict__ qbf,
    const float* __restrict__ tek, const float* __restrict__ tev,
    const float* __restrict__ mask, unsigned short* __restrict__ smix) {
  const int h = blockIdx.x, t = blockIdx.y, n = blockIdx.z;
  const int tid = threadIdx.x, w = tid >> 6, l = tid & 63;
  const int lc = l & 15, lg = l >> 4;
  constexpr int HC = HH * CC;
  __shared__ unsigned short Ks[64][72];
  __shared__ unsigned short Vt[64][72];
  __shared__ unsigned short Pl[4][64][72];

  u32x4 qf[4][2];
  {
    const unsigned short* qb = qbf + ((size_t)(n * QQ + w * 64 + lc)) * DD + h * CC + lg * 8;
    #pragma unroll
    for (int fnq = 0; fnq < 4; ++fnq)
      #pragma unroll
      for (int ks = 0; ks < 2; ++ks)
        qf[fnq][ks] = *(const u32x4*)(qb + (size_t)fnq * 16 * DD + ks * 32);
  }
  // qte[fnq] = (q*scale) . te_k
  float qte4[4];
  {
    float tkc[16];
    const float* tp = tek + (size_t)t * DD + h * CC + lg * 8;
    #pragma unroll
    for (int ks = 0; ks < 2; ++ks) {
      const float4 a = ld4(tp + ks * 32);
      const float4 b = ld4(tp + ks * 32 + 4);
      tkc[ks*8]   = a.x; tkc[ks*8+1] = a.y; tkc[ks*8+2] = a.z; tkc[ks*8+3] = a.w;
      tkc[ks*8+4] = b.x; tkc[ks*8+5] = b.y; tkc[ks*8+6] = b.z; tkc[ks*8+7] = b.w;
    }
    #pragma unroll
    for (int fnq = 0; fnq < 4; ++fnq) {
      float p = 0.f;
      #pragma unroll
      for (int ks = 0; ks < 2; ++ks)
        #pragma unroll
        for (int e = 0; e < 4; ++e) {
          const unsigned int u = qf[fnq][ks][e];
          p += bf2f(u & 0xffffu) * tkc[ks*8 + e*2];
          p += bf2f(u >> 16)     * tkc[ks*8 + e*2 + 1];
        }
      p += __shfl_xor(p, 16);
      p += __shfl_xor(p, 32);
      qte4[fnq] = p;
    }
  }

  f32x4 oacc[4][4] = {};
  float mrun[4], lrun[4];
  #pragma unroll
  for (int i = 0; i < 4; ++i) { mrun[i] = -1e30f; lrun[i] = 0.f; }

  const size_t krow0 = (((size_t)(n * TT + t) * LL + 1) * HH + h) * CC;
  const float* mbase = mask + (size_t)(w * 64) * QQ;

  for (int c0 = 0; c0 < QQ; c0 += 64) {
    __syncthreads();
    {   // stage K row-major [key][c]
      const int kr = tid >> 2, cs = (tid & 3) * 16;
      const float* kp = ak + krow0 + (size_t)(c0 + kr) * HC + cs;
      const float4 k0 = ld4(kp), k1 = ld4(kp + 4), k2 = ld4(kp + 8), k3 = ld4(kp + 12);
      u32x4 pa; pa.x = cvtpk(k0.x, k0.y); pa.y = cvtpk(k0.z, k0.w);
      pa.z = cvtpk(k1.x, k1.y); pa.w = cvtpk(k1.z, k1.w);
      u32x4 pb; pb.x = cvtpk(k2.x, k2.y); pb.y = cvtpk(k2.z, k2.w);
      pb.z = cvtpk(k3.x, k3.y); pb.w = cvtpk(k3.z, k3.w);
      *(u32x4*)&Ks[kr][cs] = pa;
      *(u32x4*)&Ks[kr][cs + 8] = pb;
    }
    {   // stage V transposed [c][key]
      const int kp2 = tid & 31, ch = tid >> 5;
      const float* vr0 = av + krow0 + (size_t)(c0 + 2 * kp2) * HC + ch * 8;
      const float* vr1 = vr0 + HC;
      const float4 a0 = ld4(vr0), a1 = ld4(vr0 + 4);
      const float4 b0 = ld4(vr1), b1 = ld4(vr1 + 4);
      const float va[8] = {a0.x,a0.y,a0.z,a0.w,a1.x,a1.y,a1.z,a1.w};
      const float vb[8] = {b0.x,b0.y,b0.z,b0.w,b1.x,b1.y,b1.z,b1.w};
      #pragma unroll
      for (int i = 0; i < 8; ++i)
        *(unsigned int*)&Vt[ch * 8 + i][2 * kp2] = cvtpk(va[i], vb[i]);
    }
    __syncthreads();

    f32x4 sf[4][4] = {};
    __builtin_amdgcn_s_setprio(1);
    #pragma unroll
    for (int ks = 0; ks < 2; ++ks) {
      u32x4 kf[4];
      #pragma unroll
      for (int fmk = 0; fmk < 4; ++fmk)
        kf[fmk] = *(const u32x4*)&Ks[fmk * 16 + lc][ks * 32 + lg * 8];
      #pragma unroll
      for (int fmk = 0; fmk < 4; ++fmk)
        #pragma unroll
        for (int fnq = 0; fnq < 4; ++fnq)
          mfma16(sf[fmk][fnq], kf[fmk], qf[fnq][ks]);
    }
    __builtin_amdgcn_s_setprio(0);

    #pragma unroll
    for (int fnq = 0; fnq < 4; ++fnq) {
      const float* mrow = mbase + (size_t)(fnq * 16 + lc) * QQ + c0 + lg * 4;
      const float qv = qte4[fnq];
      #pragma unroll
      for (int fmk = 0; fmk < 4; ++fmk) {
        const f32x4 mk = *(const f32x4*)(mrow + fmk * 16);
        sf[fmk][fnq] += mk + qv;
      }
      float mx = -1e30f;
      #pragma unroll
      for (int fmk = 0; fmk < 4; ++fmk) {
        mx = fmaxf(mx, fmaxf(fmaxf(sf[fmk][fnq][0], sf[fmk][fnq][1]),
                             fmaxf(sf[fmk][fnq][2], sf[fmk][fnq][3])));
      }
      mx = fmaxf(mx, __shfl_xor(mx, 16));
      mx = fmaxf(mx, __shfl_xor(mx, 32));
      const float mnew = fmaxf(mrun[fnq], mx);
      const float corr = __expf(mrun[fnq] - mnew);
      mrun[fnq] = mnew;
      float ls = 0.f;
      #pragma unroll
      for (int fmk = 0; fmk < 4; ++fmk) {
        const float p0 = __expf(sf[fmk][fnq][0] - mnew);
        const float p1 = __expf(sf[fmk][fnq][1] - mnew);
        const float p2 = __expf(sf[fmk][fnq][2] - mnew);
        const float p3 = __expf(sf[fmk][fnq][3] - mnew);
        ls += (p0 + p1) + (p2 + p3);
        u32x2 pw; pw.x = cvtpk(p0, p1); pw.y = cvtpk(p2, p3);
        *(u32x2*)&Pl[w][fnq * 16 + lc][fmk * 16 + lg * 4] = pw;
      }
      ls += __shfl_xor(ls, 16);
      ls += __shfl_xor(ls, 32);
      lrun[fnq] = lrun[fnq] * corr + ls;
      #pragma unroll
      for (int fmc = 0; fmc < 4; ++fmc) oacc[fmc][fnq] *= corr;
    }

    __builtin_amdgcn_s_setprio(1);
    #pragma unroll
    for (int ks = 0; ks < 2; ++ks) {
      u32x4 vf[4], pf[4];
      #pragma unroll
      for (int fmc = 0; fmc < 4; ++fmc)
        vf[fmc] = *(const u32x4*)&Vt[fmc * 16 + lc][ks * 32 + lg * 8];
      #pragma unroll
      for (int fnq = 0; fnq < 4; ++fnq)
        pf[fnq] = *(const u32x4*)&Pl[w][fnq * 16 + lc][ks * 32 + lg * 8];
      #pragma unroll
      for (int fmc = 0; fmc < 4; ++fmc)
        #pragma unroll
        for (int fnq = 0; fnq < 4; ++fnq)
          mfma16(oacc[fmc][fnq], vf[fmc], pf[fnq]);
    }
    __builtin_amdgcn_s_setprio(0);
  }

  // epilogue: O/l + te_v  -> smix bf16
  f32x4 tev4[4];
  {
    const float* tvp = tev + (size_t)t * DD + h * CC + lg * 4;
    #pragma unroll
    for (int fmc = 0; fmc < 4; ++fmc) tev4[fmc] = *(const f32x4*)(tvp + fmc * 16);
  }
  #pragma unroll
  for (int fnq = 0; fnq < 4; ++fnq) {
    const float inv = 1.f / lrun[fnq];
    const int qg = w * 64 + fnq * 16 + lc;
    unsigned short* op = smix + ((((size_t)(n * TT + t) * QQ + qg) * HH + h) * CC + lg * 4);
    #pragma unroll
    for (int fmc = 0; fmc < 4; ++fmc) {
      const f32x4 o = oacc[fmc][fnq] * inv + tev4[fmc];
      u32x2 p; p.x = cvtpk(o[0], o[1]); p.y = cvtpk(o[2], o[3]);
      *(u32x2*)(op + fmc * 16) = p;
    }
  }
}

// -------------------------------------------- conv3+mean_t combine ----
__global__ __launch_bounds__(256) void combine_kernel(
    const unsigned short* __restrict__ smix, const float* __restrict__ cw,
    const float* __restrict__ cb, unsigned short* __restrict__ smm) {
  const int nq = blockIdx.x;
  const int d = threadIdx.x * 4;
  const int n = nq >> 8, q = nq & 255;
  const unsigned short* base = smix + ((size_t)n * TT * QQ + q) * DD + d;
  float S[4] = {0.f, 0.f, 0.f, 0.f};
  float X0[4], X7[4];
  #pragma unroll
  for (int t = 0; t < TT; ++t) {
    const u32x2 pv = *(const u32x2*)(base + (size_t)t * QQ * DD);
    const float v[4] = {bf2f(pv.x & 0xffffu), bf2f(pv.x >> 16),
                        bf2f(pv.y & 0xffffu), bf2f(pv.y >> 16)};
    if (t == 0) { X0[0]=v[0]; X0[1]=v[1]; X0[2]=v[2]; X0[3]=v[3]; }
    if (t == 7) { X7[0]=v[0]; X7[1]=v[1]; X7[2]=v[2]; X7[3]=v[3]; }
    #pragma unroll
    for (int i = 0; i < 4; ++i) S[i] += v[i];
  }
  float o[4];
  #pragma unroll
  for (int i = 0; i < 4; ++i) {
    const int chn = d + i;
    const float w0 = cw[chn*3+0], w1 = cw[chn*3+1], w2 = cw[chn*3+2];
    o[i] = ((1.f + w0 + w1 + w2) * S[i] - w0 * X7[i] - w2 * X0[i]) * 0.125f + cb[chn];
  }
  u32x2 p; p.x = pk2(o[0], o[1]); p.y = pk2(o[2], o[3]);
  *(u32x2*)(smm + (size_t)nq * DD + d) = p;
}

// ------------------------------------------------------------ launch ----
extern "C" void kernel_launch(void* const* d_in, const int* in_sizes, int n_in,
                              void* d_out, int out_size, void* d_ws, size_t ws_size,
                              hipStream_t stream) {
  const float* attrs_k = (const float*)d_in[0];
  const float* attrs_v = (const float*)d_in[1];
  const float* s       = (const float*)d_in[2];
  const float* te      = (const float*)d_in[3];
  const float* pmask   = (const float*)d_in[4];
  const float* ln1_w   = (const float*)d_in[5];
  const float* ln1_b   = (const float*)d_in[6];
  const float* inW     = (const float*)d_in[7];
  const float* inB     = (const float*)d_in[8];
  const float* outW    = (const float*)d_in[9];
  const float* outB    = (const float*)d_in[10];
  const float* ln2_w   = (const float*)d_in[11];
  const float* ln2_b   = (const float*)d_in[12];
  const float* fcW     = (const float*)d_in[13];
  const float* fcB     = (const float*)d_in[14];
  const float* pjW     = (const float*)d_in[15];
  const float* pjB     = (const float*)d_in[16];
  const float* sylnW   = (const float*)d_in[17];
  const float* sylnB   = (const float*)d_in[18];
  const float* syl1    = (const float*)d_in[19];
  const float* syl2    = (const float*)d_in[20];
  const float* telnW   = (const float*)d_in[21];
  const float* telnB   = (const float*)d_in[22];
  const float* tel1    = (const float*)d_in[23];
  const float* tel2    = (const float*)d_in[24];
  const float* tconvW  = (const float*)d_in[25];
  const float* tconvB  = (const float*)d_in[26];

  float* ws = (float*)d_ws;
  float*          f_te   = ws;                                  // 8192 (= _te)
  float*          f_tek  = ws + 8192;                           // 8192
  float*          f_tev  = ws + 16384;                          // 8192
  unsigned short* telnb  = (unsigned short*)(ws + 24576);       // 4096 f
  float*          midf   = ws + 28672;                          // 1024 f
  unsigned short* syl1b  = (unsigned short*)(ws + 32768);       // 65536 f
  unsigned short* syl2b  = (unsigned short*)(ws + 98304);       // 65536 f
  unsigned short* midb   = (unsigned short*)(ws + 163840);      // 131072 f
  unsigned short* bufAb  = (unsigned short*)(ws + 327680);      // 524288 f (LN outs)
  unsigned short* qbf    = (unsigned short*)(ws + 851968);      // 524288 f
  unsigned short* smmb   = (unsigned short*)(ws + 1376256);     // 524288 f
  unsigned short* wqb    = (unsigned short*)(ws + 1900544);     // 524288 f
  unsigned short* outwb  = (unsigned short*)(ws + 2424832);     // 524288 f
  unsigned short* fcwb   = (unsigned short*)(ws + 2949120);     // 2097152 f
  unsigned short* pjwb   = (unsigned short*)(ws + 5046272);     // 2097152 f
  float*          bufB   = ws + 7143424;                        // 2097152 f (_s)
  unsigned short* smixb  = (unsigned short*)(ws + 9240576);     // 8388608 f region
  float*          s1     = ws + 9240576;                        // overlay (smix dead)
  unsigned short* hmidb  = (unsigned short*)(ws + 9240576 + 2097152); // 4194304 f
  float*          outp   = (float*)d_out;

  // 0. fused weight conversions f32 -> bf16
  cvt_all_kernel<<<10496, 256, 0, stream>>>(inW, outW, fcW, pjW, syl1, syl2,
                                            wqb, outwb, fcwb, pjwb, syl1b, syl2b);

  // 1. te adaptor pipeline + te k/v
  ln_bf_kernel<<<TT, 256, 0, stream>>>(te, telnW, telnB, telnb);
  te_mid_kernel<<<32, 256, 0, stream>>>(telnb, tel1, midf);
  te_fin_kernel<<<32, 256, 0, stream>>>(midf, tel2, te, f_te);
  te_kv2_kernel<<<64, 256, 0, stream>>>(f_te, inW, inB, f_tek, f_tev);

  // 2. syno adaptor: h = LN(s) [bf16]
  ln_bf_kernel<<<NQ, 256, 0, stream>>>(s, sylnW, sylnB, bufAb);
  // 3. mid = h @ l1^T  [bf16]
  gemm_bf<0, 64><<<32, 256, 0, stream>>>(bufAb, syl1b, nullptr, nullptr, midb, NQ, 128, DD, 32);
  // 4. _s = s + mid @ l2^T  [f32]
  gemm_bf<4, 64><<<256, 256, 0, stream>>>(midb, syl2b, nullptr, s, bufB, NQ, DD, 128, 32);
  // 5. x = LN1(_s) [bf16]
  ln_bf_kernel<<<NQ, 256, 0, stream>>>(bufB, ln1_w, ln1_b, bufAb);
  // 6. s_q = (x @ Wq^T + bq) * 0.125 [bf16]
  gemm_bf<1, 64><<<256, 256, 0, stream>>>(bufAb, wqb, inB, nullptr, qbf, NQ, DD, DD, 32);
  // 7. attention -> smix bf16 (includes te_v)
  attn_mfma<<<dim3(HH, TT, NN), 256, 0, stream>>>(attrs_k, attrs_v, qbf, f_tek, f_tev, pmask, smixb);
  // 8. conv+mean combine -> smm bf16
  combine_kernel<<<NQ, 256, 0, stream>>>(smixb, tconvW, tconvB, smmb);
  // 9. s1 = s + smm @ outW^T + outB [f32]
  gemm_bf<3, 64><<<256, 256, 0, stream>>>(smmb, outwb, outB, s, s1, NQ, DD, DD, 32);
  // 10. x2 = LN2(s1) [bf16]
  ln_bf_kernel<<<NQ, 256, 0, stream>>>(s1, ln2_w, ln2_b, bufAb);
  // 11. hmid = qgelu(x2 @ fcW^T + fcB) [bf16] (128x128 tile)
  gemm_bf<2, 128><<<512, 256, 0, stream>>>(bufAb, fcwb, fcB, nullptr, hmidb, NQ, 4 * DD, DD, 16);
  // 12. out = s1 + hmid @ pjW^T + pjB [f32]
  gemm_bf<3, 64><<<256, 256, 0, stream>>>(hmidb, pjwb, pjB, s1, outp, NQ, DD, 4 * DD, 32);
}